// Round 1
// baseline (13686.029 us; speedup 1.0000x reference)
//
#include <hip/hip_runtime.h>
#include <hip/hip_bf16.h>
#include <math.h>

#define SEQ 912
#define NTOK 911
#define CIN_ 2048
#define NLAYER 6

__device__ __forceinline__ float gelu_f(float x) {
    return 0.5f * x * (1.0f + erff(x * 0.70710678118654752f));
}

// ---------------------------------------------------------------------------
// NT GEMM: C[m,n] = sum_k A[m,k]*B[n,k] + bias[n]; optional exact GELU.
// A: (M,K) row-major, B: (N,K) row-major. 256 threads.
// ---------------------------------------------------------------------------
template <int BM, int BN, int ACT>
__global__ __launch_bounds__(256) void gemm_nt(
    const float* __restrict__ A, const float* __restrict__ B,
    const float* __restrict__ bias, float* __restrict__ C,
    int M, int N, int K)
{
    constexpr int BK = 16;
    constexpr int TM = BM / 16;
    constexpr int TN = BN / 16;
    __shared__ __align__(16) float As[BK][BM + 4];
    __shared__ __align__(16) float Bs[BK][BN + 4];
    const int t = threadIdx.x;
    const int m0 = blockIdx.y * BM;
    const int n0 = blockIdx.x * BN;
    const int tmBase = (t & 15) * 4;
    const int tnBase = (t >> 4) * 4;
    float acc[TM][TN];
#pragma unroll
    for (int i = 0; i < TM; ++i)
#pragma unroll
        for (int j = 0; j < TN; ++j) acc[i][j] = 0.f;

    constexpr int nA = (BM * BK) / 1024;   // float4 loads per thread
    constexpr int nB = (BN * BK) / 1024;

    for (int k0 = 0; k0 < K; k0 += BK) {
#pragma unroll
        for (int i = 0; i < nA; ++i) {
            int f = t + i * 256;
            int row = f >> 2;
            int kk = (f & 3) << 2;
            float4 val = make_float4(0.f, 0.f, 0.f, 0.f);
            int gr = m0 + row;
            if (gr < M) val = *(const float4*)(A + (size_t)gr * K + k0 + kk);
            As[kk + 0][row] = val.x; As[kk + 1][row] = val.y;
            As[kk + 2][row] = val.z; As[kk + 3][row] = val.w;
        }
#pragma unroll
        for (int i = 0; i < nB; ++i) {
            int f = t + i * 256;
            int row = f >> 2;
            int kk = (f & 3) << 2;
            float4 val = make_float4(0.f, 0.f, 0.f, 0.f);
            int gn = n0 + row;
            if (gn < N) val = *(const float4*)(B + (size_t)gn * K + k0 + kk);
            Bs[kk + 0][row] = val.x; Bs[kk + 1][row] = val.y;
            Bs[kk + 2][row] = val.z; Bs[kk + 3][row] = val.w;
        }
        __syncthreads();
#pragma unroll
        for (int kk = 0; kk < BK; ++kk) {
            float a[TM], b[TN];
#pragma unroll
            for (int g = 0; g < TM / 4; ++g) {
                float4 av = *(const float4*)&As[kk][tmBase + g * (BM / 2)];
                a[g * 4 + 0] = av.x; a[g * 4 + 1] = av.y;
                a[g * 4 + 2] = av.z; a[g * 4 + 3] = av.w;
            }
#pragma unroll
            for (int g = 0; g < TN / 4; ++g) {
                float4 bv = *(const float4*)&Bs[kk][tnBase + g * (BN / 2)];
                b[g * 4 + 0] = bv.x; b[g * 4 + 1] = bv.y;
                b[g * 4 + 2] = bv.z; b[g * 4 + 3] = bv.w;
            }
#pragma unroll
            for (int i = 0; i < TM; ++i)
#pragma unroll
                for (int j = 0; j < TN; ++j)
                    acc[i][j] = fmaf(a[i], b[j], acc[i][j]);
        }
        __syncthreads();
    }
#pragma unroll
    for (int i = 0; i < TM; ++i) {
        int gm = m0 + tmBase + (i >> 2) * (BM / 2) + (i & 3);
        if (gm >= M) continue;
#pragma unroll
        for (int gj = 0; gj < TN / 4; ++gj) {
            int gn = n0 + tnBase + gj * (BN / 2);
            float4 o;
            o.x = acc[i][gj * 4 + 0]; o.y = acc[i][gj * 4 + 1];
            o.z = acc[i][gj * 4 + 2]; o.w = acc[i][gj * 4 + 3];
            const float4 bv = *(const float4*)(bias + gn);
            o.x += bv.x; o.y += bv.y; o.z += bv.z; o.w += bv.w;
            if (ACT == 1) {
                o.x = gelu_f(o.x); o.y = gelu_f(o.y);
                o.z = gelu_f(o.z); o.w = gelu_f(o.w);
            }
            *(float4*)(C + (size_t)gm * N + gn) = o;
        }
    }
}

// ---------------------------------------------------------------------------
// Transpose feat (B,CIN,H,W) -> patch rows (b*911 + tok_off + p, CIN)
// ---------------------------------------------------------------------------
__global__ __launch_bounds__(256) void transpose_feat_kernel(
    const float* __restrict__ feat, float* __restrict__ patch, int HW, int tok_off)
{
    __shared__ float tile[32][33];
    const int b = blockIdx.z;
    const int c0 = blockIdx.y * 32;
    const int p0 = blockIdx.x * 32;
    const int tx = threadIdx.x, ty = threadIdx.y;
#pragma unroll
    for (int i = 0; i < 4; ++i) {
        int c = c0 + ty + i * 8;
        int p = p0 + tx;
        tile[ty + i * 8][tx] = (p < HW) ? feat[((size_t)b * CIN_ + c) * HW + p] : 0.f;
    }
    __syncthreads();
#pragma unroll
    for (int i = 0; i < 4; ++i) {
        int p = p0 + ty + i * 8;
        int c = c0 + tx;
        if (p < HW)
            patch[((size_t)(b * NTOK + tok_off + p)) * CIN_ + c] = tile[tx][ty + i * 8];
    }
}

// ---------------------------------------------------------------------------
// Assemble x (B,912,512): cls token + tok + channel emb + pos emb
// ---------------------------------------------------------------------------
__global__ __launch_bounds__(128) void build_x_kernel(
    const float* __restrict__ tok, const float* __restrict__ cls_token,
    const float* __restrict__ emb_org, const float* __restrict__ emb_r1,
    const float* __restrict__ emb_r2, const float* __restrict__ pos_emb,
    float* __restrict__ x)
{
    const int row = blockIdx.x;
    const int b = row / SEQ;
    const int tt = row - b * SEQ;
    const int d4 = threadIdx.x;
    float4 o;
    if (tt == 0) {
        o = ((const float4*)cls_token)[d4];
    } else {
        int tp = tt - 1;
        const float* ce; int hh, ww, p;
        if (tp < 768)      { p = tp;       hh = 24; ww = 32; ce = emb_org; }
        else if (tp < 876) { p = tp - 768; hh = 9;  ww = 12; ce = emb_r1; }
        else               { p = tp - 876; hh = 5;  ww = 7;  ce = emb_r2; }
        int i = p / ww, j = p - i * ww;
        int ti = (i * 10) / hh, tj = (j * 10) / ww;
        float4 tv = ((const float4*)(tok + (size_t)(b * NTOK + tp) * 512))[d4];
        float4 cv = ((const float4*)ce)[d4];
        float4 pv = ((const float4*)(pos_emb + (size_t)(ti * 10 + tj) * 512))[d4];
        o.x = tv.x + cv.x + pv.x; o.y = tv.y + cv.y + pv.y;
        o.z = tv.z + cv.z + pv.z; o.w = tv.w + cv.w + pv.w;
    }
    ((float4*)(x + (size_t)row * 512))[d4] = o;
}

// ---------------------------------------------------------------------------
// Attention: 8 queries per block, full softmax over 912 keys in LDS.
// q,k,v: (B*SEQ, 512) with head h at columns [h*64, h*64+64)
// ---------------------------------------------------------------------------
__global__ __launch_bounds__(256) void attn_kernel(
    const float* __restrict__ q, const float* __restrict__ k,
    const float* __restrict__ v, const int* __restrict__ mask,
    float* __restrict__ ctx)
{
    __shared__ float qs[8][64];
    __shared__ float ks[32][65];
    __shared__ float sc[8][SEQ];
    __shared__ float sinv[8];
    const int bid = blockIdx.x;
    const int qb = bid % 114;
    const int h = (bid / 114) & 7;
    const int b = bid / (114 * 8);
    const int q0 = qb * 8;
    const int t = threadIdx.x;

    for (int i = t; i < 512; i += 256) {
        int qi = i >> 6, d = i & 63;
        qs[qi][d] = q[((size_t)(b * SEQ + q0 + qi)) * 512 + h * 64 + d] * 0.125f;
    }
    __syncthreads();
    const int qi = t >> 5, kl = t & 31;
    for (int kb = 0; kb < SEQ; kb += 32) {
        for (int i = t; i < 2048; i += 256) {
            int kr = i >> 6, d = i & 63;
            int kg = kb + kr;
            ks[kr][d] = (kg < SEQ) ? k[((size_t)(b * SEQ + kg)) * 512 + h * 64 + d] : 0.f;
        }
        __syncthreads();
        int kg = kb + kl;
        float s = 0.f;
#pragma unroll
        for (int d = 0; d < 64; ++d) s = fmaf(qs[qi][d], ks[kl][d], s);
        if (kg < SEQ) sc[qi][kg] = (mask[b * SEQ + kg] != 0) ? s : -1e9f;
        __syncthreads();
    }
    // softmax per row (32 threads per row; contiguous half-wave)
    float mx = -1e30f;
    for (int j = kl; j < SEQ; j += 32) mx = fmaxf(mx, sc[qi][j]);
#pragma unroll
    for (int o = 16; o; o >>= 1) mx = fmaxf(mx, __shfl_xor(mx, o, 64));
    float sum = 0.f;
    for (int j = kl; j < SEQ; j += 32) {
        float e = __expf(sc[qi][j] - mx);
        sc[qi][j] = e;
        sum += e;
    }
#pragma unroll
    for (int o = 16; o; o >>= 1) sum += __shfl_xor(sum, o, 64);
    if (kl == 0) sinv[qi] = 1.f / sum;

    // ctx accumulation: thread = (qg = t>>6 handles rows qg, qg+4; d = t&63)
    const int d = t & 63;
    const int qg = t >> 6;
    float acc0 = 0.f, acc1 = 0.f;
    for (int kb = 0; kb < SEQ; kb += 32) {
        __syncthreads();
        for (int i = t; i < 2048; i += 256) {
            int kr = i >> 6, dd = i & 63;
            int kg = kb + kr;
            ks[kr][dd] = (kg < SEQ) ? v[((size_t)(b * SEQ + kg)) * 512 + h * 64 + dd] : 0.f;
        }
        __syncthreads();
        int lim = (SEQ - kb < 32) ? (SEQ - kb) : 32;
        for (int kl2 = 0; kl2 < lim; ++kl2) {
            float vv = ks[kl2][d];
            acc0 = fmaf(sc[qg][kb + kl2], vv, acc0);
            acc1 = fmaf(sc[qg + 4][kb + kl2], vv, acc1);
        }
    }
    acc0 *= sinv[qg];
    acc1 *= sinv[qg + 4];
    ctx[((size_t)(b * SEQ + q0 + qg)) * 512 + h * 64 + d] = acc0;
    ctx[((size_t)(b * SEQ + q0 + qg + 4)) * 512 + h * 64 + d] = acc1;
}

// ---------------------------------------------------------------------------
// x = LN(x + r) * g + beta, one wave per 512-wide row
// ---------------------------------------------------------------------------
__global__ __launch_bounds__(64) void ln_residual_kernel(
    float* __restrict__ x, const float* __restrict__ r,
    const float* __restrict__ g, const float* __restrict__ bta)
{
    const int row = blockIdx.x;
    const int t = threadIdx.x;
    float4* xr = (float4*)(x + (size_t)row * 512);
    const float4* rr = (const float4*)(r + (size_t)row * 512);
    float4 a0 = xr[t], a1 = xr[t + 64];
    float4 b0 = rr[t], b1 = rr[t + 64];
    a0.x += b0.x; a0.y += b0.y; a0.z += b0.z; a0.w += b0.w;
    a1.x += b1.x; a1.y += b1.y; a1.z += b1.z; a1.w += b1.w;
    float s = a0.x + a0.y + a0.z + a0.w + a1.x + a1.y + a1.z + a1.w;
#pragma unroll
    for (int o = 32; o; o >>= 1) s += __shfl_xor(s, o, 64);
    const float mean = s * (1.f / 512.f);
    float sq = 0.f;
    sq += (a0.x - mean) * (a0.x - mean); sq += (a0.y - mean) * (a0.y - mean);
    sq += (a0.z - mean) * (a0.z - mean); sq += (a0.w - mean) * (a0.w - mean);
    sq += (a1.x - mean) * (a1.x - mean); sq += (a1.y - mean) * (a1.y - mean);
    sq += (a1.z - mean) * (a1.z - mean); sq += (a1.w - mean) * (a1.w - mean);
#pragma unroll
    for (int o = 32; o; o >>= 1) sq += __shfl_xor(sq, o, 64);
    const float rstd = rsqrtf(sq * (1.f / 512.f) + 1e-6f);
    const float4 g0 = ((const float4*)g)[t], g1 = ((const float4*)g)[t + 64];
    const float4 e0 = ((const float4*)bta)[t], e1 = ((const float4*)bta)[t + 64];
    float4 o0, o1;
    o0.x = (a0.x - mean) * rstd * g0.x + e0.x;
    o0.y = (a0.y - mean) * rstd * g0.y + e0.y;
    o0.z = (a0.z - mean) * rstd * g0.z + e0.z;
    o0.w = (a0.w - mean) * rstd * g0.w + e0.w;
    o1.x = (a1.x - mean) * rstd * g1.x + e1.x;
    o1.y = (a1.y - mean) * rstd * g1.y + e1.y;
    o1.z = (a1.z - mean) * rstd * g1.z + e1.z;
    o1.w = (a1.w - mean) * rstd * g1.w + e1.w;
    xr[t] = o0; xr[t + 64] = o1;
}

// ---------------------------------------------------------------------------
// Head: hmlp[b,n] = gelu(dot(x[b,0,:], proj_w1[n,:])); pred[b] = dot(hmlp, pw2)
// ---------------------------------------------------------------------------
__global__ __launch_bounds__(64) void head1_kernel(
    const float* __restrict__ x, const float* __restrict__ w,
    float* __restrict__ hmlp)
{
    const int n = blockIdx.x & 1023;
    const int b = blockIdx.x >> 10;
    const int t = threadIdx.x;
    const float4* cls = (const float4*)(x + (size_t)b * SEQ * 512);
    const float4* wr = (const float4*)(w + (size_t)n * 512);
    float s = 0.f;
#pragma unroll
    for (int i = 0; i < 2; ++i) {
        float4 a = cls[t + i * 64], c = wr[t + i * 64];
        s += a.x * c.x + a.y * c.y + a.z * c.z + a.w * c.w;
    }
#pragma unroll
    for (int o = 32; o; o >>= 1) s += __shfl_xor(s, o, 64);
    if (t == 0) hmlp[b * 1024 + n] = gelu_f(s);
}

__global__ __launch_bounds__(256) void head2_kernel(
    const float* __restrict__ hmlp, const float* __restrict__ w,
    float* __restrict__ out)
{
    __shared__ float red[4];
    const int b = blockIdx.x;
    const int t = threadIdx.x;
    float s = 0.f;
    for (int i = t; i < 1024; i += 256) s += hmlp[b * 1024 + i] * w[i];
#pragma unroll
    for (int o = 32; o; o >>= 1) s += __shfl_xor(s, o, 64);
    if ((t & 63) == 0) red[t >> 6] = s;
    __syncthreads();
    if (t == 0) out[b] = red[0] + red[1] + red[2] + red[3];
}

// ---------------------------------------------------------------------------
extern "C" void kernel_launch(void* const* d_in, const int* in_sizes, int n_in,
                              void* d_out, int out_size, void* d_ws, size_t ws_size,
                              hipStream_t stream)
{
    const float* feat_org = (const float*)d_in[0];
    const float* feat_r1  = (const float*)d_in[1];
    const float* feat_r2  = (const float*)d_in[2];
    const float* conv_w   = (const float*)d_in[3];
    const float* conv_b   = (const float*)d_in[4];
    const float* emb_org  = (const float*)d_in[5];
    const float* emb_r1   = (const float*)d_in[6];
    const float* emb_r2   = (const float*)d_in[7];
    const float* pos_emb  = (const float*)d_in[8];
    const float* cls_tok  = (const float*)d_in[9];
    const float* Wq = (const float*)d_in[10];
    const float* bq = (const float*)d_in[11];
    const float* Wk = (const float*)d_in[12];
    const float* bk = (const float*)d_in[13];
    const float* Wv = (const float*)d_in[14];
    const float* bv = (const float*)d_in[15];
    const float* Wo = (const float*)d_in[16];
    const float* bo = (const float*)d_in[17];
    const float* ln1g = (const float*)d_in[18];
    const float* ln1b = (const float*)d_in[19];
    const float* w1 = (const float*)d_in[20];
    const float* b1 = (const float*)d_in[21];
    const float* w2 = (const float*)d_in[22];
    const float* b2 = (const float*)d_in[23];
    const float* ln2g = (const float*)d_in[24];
    const float* ln2b = (const float*)d_in[25];
    const float* pw1 = (const float*)d_in[26];
    const float* pw2 = (const float*)d_in[27];
    const int*   mask = (const int*)d_in[28];

    float* ws = (float*)d_ws;
    // workspace layout (floats)
    float* ffh   = ws;                     // 7296*2048 = 14,942,208 (also patch)
    float* patch = ws;                     // 7288*2048 fits in ffh region
    float* x     = ws + 14942208;          // 7296*512
    float* qb_   = x + 3735552;
    float* kb_   = qb_ + 3735552;
    float* vb_   = kb_ + 3735552;
    float* ctx   = vb_ + 3735552;
    float* hmlp  = ctx + 3735552;          // 8192

    dim3 tb(32, 8);
    hipLaunchKernelGGL(transpose_feat_kernel, dim3(24, 64, 8), tb, 0, stream,
                       feat_org, patch, 768, 0);
    hipLaunchKernelGGL(transpose_feat_kernel, dim3(4, 64, 8), tb, 0, stream,
                       feat_r1, patch, 108, 768);
    hipLaunchKernelGGL(transpose_feat_kernel, dim3(2, 64, 8), tb, 0, stream,
                       feat_r2, patch, 35, 876);

    // embed GEMM -> tok (stored in qb_)
    hipLaunchKernelGGL((gemm_nt<64, 128, 0>), dim3(4, 114), 256, 0, stream,
                       patch, conv_w, conv_b, qb_, 7288, 512, 2048);
    hipLaunchKernelGGL(build_x_kernel, dim3(7296), 128, 0, stream,
                       qb_, cls_tok, emb_org, emb_r1, emb_r2, pos_emb, x);

    for (int l = 0; l < NLAYER; ++l) {
        const float* Wq_l = Wq + (size_t)l * 512 * 512;
        const float* Wk_l = Wk + (size_t)l * 512 * 512;
        const float* Wv_l = Wv + (size_t)l * 512 * 512;
        const float* Wo_l = Wo + (size_t)l * 512 * 512;
        const float* w1_l = w1 + (size_t)l * 2048 * 512;
        const float* w2_l = w2 + (size_t)l * 512 * 2048;

        hipLaunchKernelGGL((gemm_nt<64, 128, 0>), dim3(4, 114), 256, 0, stream,
                           x, Wq_l, bq + l * 512, qb_, 7296, 512, 512);
        hipLaunchKernelGGL((gemm_nt<64, 128, 0>), dim3(4, 114), 256, 0, stream,
                           x, Wk_l, bk + l * 512, kb_, 7296, 512, 512);
        hipLaunchKernelGGL((gemm_nt<64, 128, 0>), dim3(4, 114), 256, 0, stream,
                           x, Wv_l, bv + l * 512, vb_, 7296, 512, 512);
        hipLaunchKernelGGL(attn_kernel, dim3(8 * 8 * 114), 256, 0, stream,
                           qb_, kb_, vb_, mask, ctx);
        hipLaunchKernelGGL((gemm_nt<64, 128, 0>), dim3(4, 114), 256, 0, stream,
                           ctx, Wo_l, bo + l * 512, qb_, 7296, 512, 512);
        hipLaunchKernelGGL(ln_residual_kernel, dim3(7296), 64, 0, stream,
                           x, qb_, ln1g + l * 512, ln1b + l * 512);
        hipLaunchKernelGGL((gemm_nt<128, 128, 1>), dim3(16, 57), 256, 0, stream,
                           x, w1_l, b1 + l * 2048, ffh, 7296, 2048, 512);
        hipLaunchKernelGGL((gemm_nt<64, 128, 0>), dim3(4, 114), 256, 0, stream,
                           ffh, w2_l, b2 + l * 512, qb_, 7296, 512, 2048);
        hipLaunchKernelGGL(ln_residual_kernel, dim3(7296), 64, 0, stream,
                           x, qb_, ln2g + l * 512, ln2b + l * 512);
    }

    hipLaunchKernelGGL(head1_kernel, dim3(8 * 1024), 64, 0, stream, x, pw1, hmlp);
    hipLaunchKernelGGL(head2_kernel, dim3(8), 256, 0, stream, hmlp, pw2, (float*)d_out);
}

// Round 2
// 6785.062 us; speedup vs baseline: 2.0171x; 2.0171x over previous
//
#include <hip/hip_runtime.h>
#include <hip/hip_bf16.h>
#include <math.h>

#define SEQ 912
#define NTOK 911
#define CIN_ 2048
#define NLAYER 6

__device__ __forceinline__ float gelu_f(float x) {
    return 0.5f * x * (1.0f + erff(x * 0.70710678118654752f));
}

// ---------------------------------------------------------------------------
// NT GEMM: C[m,n] = sum_k A[m,k]*B[n,k] + bias[n]; optional exact GELU.
// A: (M,K) row-major, B: (N,K) row-major. 256 threads.
// ---------------------------------------------------------------------------
template <int BM, int BN, int ACT>
__global__ __launch_bounds__(256) void gemm_nt(
    const float* __restrict__ A, const float* __restrict__ B,
    const float* __restrict__ bias, float* __restrict__ C,
    int M, int N, int K)
{
    constexpr int BK = 16;
    constexpr int TM = BM / 16;
    constexpr int TN = BN / 16;
    __shared__ __align__(16) float As[BK][BM + 4];
    __shared__ __align__(16) float Bs[BK][BN + 4];
    const int t = threadIdx.x;
    const int m0 = blockIdx.y * BM;
    const int n0 = blockIdx.x * BN;
    const int tmBase = (t & 15) * 4;
    const int tnBase = (t >> 4) * 4;
    float acc[TM][TN];
#pragma unroll
    for (int i = 0; i < TM; ++i)
#pragma unroll
        for (int j = 0; j < TN; ++j) acc[i][j] = 0.f;

    constexpr int nA = (BM * BK) / 1024;   // float4 loads per thread
    constexpr int nB = (BN * BK) / 1024;

    for (int k0 = 0; k0 < K; k0 += BK) {
#pragma unroll
        for (int i = 0; i < nA; ++i) {
            int f = t + i * 256;
            int row = f >> 2;
            int kk = (f & 3) << 2;
            float4 val = make_float4(0.f, 0.f, 0.f, 0.f);
            int gr = m0 + row;
            if (gr < M) val = *(const float4*)(A + (size_t)gr * K + k0 + kk);
            As[kk + 0][row] = val.x; As[kk + 1][row] = val.y;
            As[kk + 2][row] = val.z; As[kk + 3][row] = val.w;
        }
#pragma unroll
        for (int i = 0; i < nB; ++i) {
            int f = t + i * 256;
            int row = f >> 2;
            int kk = (f & 3) << 2;
            float4 val = make_float4(0.f, 0.f, 0.f, 0.f);
            int gn = n0 + row;
            if (gn < N) val = *(const float4*)(B + (size_t)gn * K + k0 + kk);
            Bs[kk + 0][row] = val.x; Bs[kk + 1][row] = val.y;
            Bs[kk + 2][row] = val.z; Bs[kk + 3][row] = val.w;
        }
        __syncthreads();
#pragma unroll
        for (int kk = 0; kk < BK; ++kk) {
            float a[TM], b[TN];
#pragma unroll
            for (int g = 0; g < TM / 4; ++g) {
                float4 av = *(const float4*)&As[kk][tmBase + g * (BM / 2)];
                a[g * 4 + 0] = av.x; a[g * 4 + 1] = av.y;
                a[g * 4 + 2] = av.z; a[g * 4 + 3] = av.w;
            }
#pragma unroll
            for (int g = 0; g < TN / 4; ++g) {
                float4 bv = *(const float4*)&Bs[kk][tnBase + g * (BN / 2)];
                b[g * 4 + 0] = bv.x; b[g * 4 + 1] = bv.y;
                b[g * 4 + 2] = bv.z; b[g * 4 + 3] = bv.w;
            }
#pragma unroll
            for (int i = 0; i < TM; ++i)
#pragma unroll
                for (int j = 0; j < TN; ++j)
                    acc[i][j] = fmaf(a[i], b[j], acc[i][j]);
        }
        __syncthreads();
    }
#pragma unroll
    for (int i = 0; i < TM; ++i) {
        int gm = m0 + tmBase + (i >> 2) * (BM / 2) + (i & 3);
        if (gm >= M) continue;
#pragma unroll
        for (int gj = 0; gj < TN / 4; ++gj) {
            int gn = n0 + tnBase + gj * (BN / 2);
            float4 o;
            o.x = acc[i][gj * 4 + 0]; o.y = acc[i][gj * 4 + 1];
            o.z = acc[i][gj * 4 + 2]; o.w = acc[i][gj * 4 + 3];
            const float4 bv = *(const float4*)(bias + gn);
            o.x += bv.x; o.y += bv.y; o.z += bv.z; o.w += bv.w;
            if (ACT == 1) {
                o.x = gelu_f(o.x); o.y = gelu_f(o.y);
                o.z = gelu_f(o.z); o.w = gelu_f(o.w);
            }
            *(float4*)(C + (size_t)gm * N + gn) = o;
        }
    }
}

// ---------------------------------------------------------------------------
// Transpose feat (B,CIN,H,W) -> patch rows (b*911 + tok_off + p, CIN)
// ---------------------------------------------------------------------------
__global__ __launch_bounds__(256) void transpose_feat_kernel(
    const float* __restrict__ feat, float* __restrict__ patch, int HW, int tok_off)
{
    __shared__ float tile[32][33];
    const int b = blockIdx.z;
    const int c0 = blockIdx.y * 32;
    const int p0 = blockIdx.x * 32;
    const int tx = threadIdx.x, ty = threadIdx.y;
#pragma unroll
    for (int i = 0; i < 4; ++i) {
        int c = c0 + ty + i * 8;
        int p = p0 + tx;
        tile[ty + i * 8][tx] = (p < HW) ? feat[((size_t)b * CIN_ + c) * HW + p] : 0.f;
    }
    __syncthreads();
#pragma unroll
    for (int i = 0; i < 4; ++i) {
        int p = p0 + ty + i * 8;
        int c = c0 + tx;
        if (p < HW)
            patch[((size_t)(b * NTOK + tok_off + p)) * CIN_ + c] = tile[tx][ty + i * 8];
    }
}

// ---------------------------------------------------------------------------
// Assemble x (B,912,512): cls token + tok + channel emb + pos emb
// ---------------------------------------------------------------------------
__global__ __launch_bounds__(128) void build_x_kernel(
    const float* __restrict__ tok, const float* __restrict__ cls_token,
    const float* __restrict__ emb_org, const float* __restrict__ emb_r1,
    const float* __restrict__ emb_r2, const float* __restrict__ pos_emb,
    float* __restrict__ x)
{
    const int row = blockIdx.x;
    const int b = row / SEQ;
    const int tt = row - b * SEQ;
    const int d4 = threadIdx.x;
    float4 o;
    if (tt == 0) {
        o = ((const float4*)cls_token)[d4];
    } else {
        int tp = tt - 1;
        const float* ce; int hh, ww, p;
        if (tp < 768)      { p = tp;       hh = 24; ww = 32; ce = emb_org; }
        else if (tp < 876) { p = tp - 768; hh = 9;  ww = 12; ce = emb_r1; }
        else               { p = tp - 876; hh = 5;  ww = 7;  ce = emb_r2; }
        int i = p / ww, j = p - i * ww;
        int ti = (i * 10) / hh, tj = (j * 10) / ww;
        float4 tv = ((const float4*)(tok + (size_t)(b * NTOK + tp) * 512))[d4];
        float4 cv = ((const float4*)ce)[d4];
        float4 pv = ((const float4*)(pos_emb + (size_t)(ti * 10 + tj) * 512))[d4];
        o.x = tv.x + cv.x + pv.x; o.y = tv.y + cv.y + pv.y;
        o.z = tv.z + cv.z + pv.z; o.w = tv.w + cv.w + pv.w;
    }
    ((float4*)(x + (size_t)row * 512))[d4] = o;
}

// ---------------------------------------------------------------------------
// Flash attention, fp32 register-tiled.
// Block = one (b,h) x 64-query tile. 256 threads: tx=t&15 -> cols 4tx..4tx+3,
// ty=t>>4 -> rows 4ty..4ty+3. Q,K stored transposed in LDS; P transposed too.
// ---------------------------------------------------------------------------
__global__ __launch_bounds__(256) void attn_flash(
    const float* __restrict__ q, const float* __restrict__ k,
    const float* __restrict__ v, const int* __restrict__ mask,
    float* __restrict__ ctx)
{
    constexpr int P = 68;
    __shared__ __align__(16) float qsT[64][P];   // qsT[d][row] (pre-scaled)
    __shared__ __align__(16) float kv[64][P];    // K: [d][col]; V: [key][d]
    __shared__ __align__(16) float psT[64][P];   // psT[key][row]
    const int qt = blockIdx.x, h = blockIdx.y, b = blockIdx.z;
    const int q0 = qt * 64;
    const int t = threadIdx.x;
    const int tx4 = (t & 15) * 4;
    const int ty4 = (t >> 4) * 4;

    // load Q transposed, scaled
#pragma unroll
    for (int it = 0; it < 4; ++it) {
        int flat = t + it * 256;
        int r = flat >> 4;
        int ch = (flat & 15) << 2;
        int gq = q0 + r;
        float4 val = make_float4(0.f, 0.f, 0.f, 0.f);
        if (gq < SEQ) val = *(const float4*)(q + ((size_t)(b * SEQ + gq)) * 512 + h * 64 + ch);
        qsT[ch + 0][r] = val.x * 0.125f;
        qsT[ch + 1][r] = val.y * 0.125f;
        qsT[ch + 2][r] = val.z * 0.125f;
        qsT[ch + 3][r] = val.w * 0.125f;
    }

    float m_i[4], l_i[4], o[4][4];
#pragma unroll
    for (int i = 0; i < 4; ++i) {
        m_i[i] = -1e30f; l_i[i] = 0.f;
#pragma unroll
        for (int j = 0; j < 4; ++j) o[i][j] = 0.f;
    }

    for (int kb = 0; kb < 960; kb += 64) {
        __syncthreads();   // previous PV reads of kv done
        // load K-tile transposed
#pragma unroll
        for (int it = 0; it < 4; ++it) {
            int flat = t + it * 256;
            int r = flat >> 4;
            int ch = (flat & 15) << 2;
            int kg = kb + r;
            float4 val = make_float4(0.f, 0.f, 0.f, 0.f);
            if (kg < SEQ) val = *(const float4*)(k + ((size_t)(b * SEQ + kg)) * 512 + h * 64 + ch);
            kv[ch + 0][r] = val.x; kv[ch + 1][r] = val.y;
            kv[ch + 2][r] = val.z; kv[ch + 3][r] = val.w;
        }
        __syncthreads();

        // S = Q K^T tile (4x4 per thread)
        float s[4][4];
#pragma unroll
        for (int i = 0; i < 4; ++i)
#pragma unroll
            for (int j = 0; j < 4; ++j) s[i][j] = 0.f;
#pragma unroll 16
        for (int d = 0; d < 64; ++d) {
            float4 qv = *(const float4*)&qsT[d][ty4];
            float4 kk_ = *(const float4*)&kv[d][tx4];
            float qa[4] = {qv.x, qv.y, qv.z, qv.w};
            float ka[4] = {kk_.x, kk_.y, kk_.z, kk_.w};
#pragma unroll
            for (int i = 0; i < 4; ++i)
#pragma unroll
                for (int j = 0; j < 4; ++j)
                    s[i][j] = fmaf(qa[i], ka[j], s[i][j]);
        }

        // mask/pad bias per column
        float bias[4];
#pragma unroll
        for (int j = 0; j < 4; ++j) {
            int kg = kb + tx4 + j;
            bias[j] = (kg < SEQ) ? (mask[b * SEQ + kg] ? 0.f : -1e9f) : -2e9f;
        }

        // online softmax update
#pragma unroll
        for (int i = 0; i < 4; ++i) {
            float mx = -3e38f;
#pragma unroll
            for (int j = 0; j < 4; ++j) { s[i][j] += bias[j]; mx = fmaxf(mx, s[i][j]); }
            mx = fmaxf(mx, __shfl_xor(mx, 1, 64));
            mx = fmaxf(mx, __shfl_xor(mx, 2, 64));
            mx = fmaxf(mx, __shfl_xor(mx, 4, 64));
            mx = fmaxf(mx, __shfl_xor(mx, 8, 64));
            float mnew = fmaxf(m_i[i], mx);
            float alpha = __expf(m_i[i] - mnew);
            m_i[i] = mnew;
            float sum = 0.f;
#pragma unroll
            for (int j = 0; j < 4; ++j) {
                s[i][j] = __expf(s[i][j] - mnew);
                sum += s[i][j];
            }
            sum += __shfl_xor(sum, 1, 64);
            sum += __shfl_xor(sum, 2, 64);
            sum += __shfl_xor(sum, 4, 64);
            sum += __shfl_xor(sum, 8, 64);
            l_i[i] = l_i[i] * alpha + sum;
#pragma unroll
            for (int j = 0; j < 4; ++j) o[i][j] *= alpha;
        }

        // store P transposed: psT[col][row]
#pragma unroll
        for (int j = 0; j < 4; ++j) {
            float4 pv = make_float4(s[0][j], s[1][j], s[2][j], s[3][j]);
            *(float4*)&psT[tx4 + j][ty4] = pv;
        }
        __syncthreads();   // kv K-reads + psT writes done

        // load V-tile natural: kv[key][d]
#pragma unroll
        for (int it = 0; it < 4; ++it) {
            int flat = t + it * 256;
            int r = flat >> 4;
            int ch = (flat & 15) << 2;
            int kg = kb + r;
            float4 val = make_float4(0.f, 0.f, 0.f, 0.f);
            if (kg < SEQ) val = *(const float4*)(v + ((size_t)(b * SEQ + kg)) * 512 + h * 64 + ch);
            *(float4*)&kv[r][ch] = val;
        }
        __syncthreads();

        // O += P V
#pragma unroll 16
        for (int kk = 0; kk < 64; ++kk) {
            float4 pp = *(const float4*)&psT[kk][ty4];
            float4 vv = *(const float4*)&kv[kk][tx4];
            float pa[4] = {pp.x, pp.y, pp.z, pp.w};
            float va[4] = {vv.x, vv.y, vv.z, vv.w};
#pragma unroll
            for (int i = 0; i < 4; ++i)
#pragma unroll
                for (int j = 0; j < 4; ++j)
                    o[i][j] = fmaf(pa[i], va[j], o[i][j]);
        }
    }

    // epilogue
#pragma unroll
    for (int i = 0; i < 4; ++i) {
        int row = q0 + ty4 + i;
        if (row < SEQ) {
            float inv = 1.f / l_i[i];
            float4 ov = make_float4(o[i][0] * inv, o[i][1] * inv,
                                    o[i][2] * inv, o[i][3] * inv);
            *(float4*)(ctx + ((size_t)(b * SEQ + row)) * 512 + h * 64 + tx4) = ov;
        }
    }
}

// ---------------------------------------------------------------------------
// x = LN(x + r) * g + beta, one wave per 512-wide row
// ---------------------------------------------------------------------------
__global__ __launch_bounds__(64) void ln_residual_kernel(
    float* __restrict__ x, const float* __restrict__ r,
    const float* __restrict__ g, const float* __restrict__ bta)
{
    const int row = blockIdx.x;
    const int t = threadIdx.x;
    float4* xr = (float4*)(x + (size_t)row * 512);
    const float4* rr = (const float4*)(r + (size_t)row * 512);
    float4 a0 = xr[t], a1 = xr[t + 64];
    float4 b0 = rr[t], b1 = rr[t + 64];
    a0.x += b0.x; a0.y += b0.y; a0.z += b0.z; a0.w += b0.w;
    a1.x += b1.x; a1.y += b1.y; a1.z += b1.z; a1.w += b1.w;
    float s = a0.x + a0.y + a0.z + a0.w + a1.x + a1.y + a1.z + a1.w;
#pragma unroll
    for (int o = 32; o; o >>= 1) s += __shfl_xor(s, o, 64);
    const float mean = s * (1.f / 512.f);
    float sq = 0.f;
    sq += (a0.x - mean) * (a0.x - mean); sq += (a0.y - mean) * (a0.y - mean);
    sq += (a0.z - mean) * (a0.z - mean); sq += (a0.w - mean) * (a0.w - mean);
    sq += (a1.x - mean) * (a1.x - mean); sq += (a1.y - mean) * (a1.y - mean);
    sq += (a1.z - mean) * (a1.z - mean); sq += (a1.w - mean) * (a1.w - mean);
#pragma unroll
    for (int o = 32; o; o >>= 1) sq += __shfl_xor(sq, o, 64);
    const float rstd = rsqrtf(sq * (1.f / 512.f) + 1e-6f);
    const float4 g0 = ((const float4*)g)[t], g1 = ((const float4*)g)[t + 64];
    const float4 e0 = ((const float4*)bta)[t], e1 = ((const float4*)bta)[t + 64];
    float4 o0, o1;
    o0.x = (a0.x - mean) * rstd * g0.x + e0.x;
    o0.y = (a0.y - mean) * rstd * g0.y + e0.y;
    o0.z = (a0.z - mean) * rstd * g0.z + e0.z;
    o0.w = (a0.w - mean) * rstd * g0.w + e0.w;
    o1.x = (a1.x - mean) * rstd * g1.x + e1.x;
    o1.y = (a1.y - mean) * rstd * g1.y + e1.y;
    o1.z = (a1.z - mean) * rstd * g1.z + e1.z;
    o1.w = (a1.w - mean) * rstd * g1.w + e1.w;
    xr[t] = o0; xr[t + 64] = o1;
}

// ---------------------------------------------------------------------------
// Head: hmlp[b,n] = gelu(dot(x[b,0,:], proj_w1[n,:])); pred[b] = dot(hmlp, pw2)
// ---------------------------------------------------------------------------
__global__ __launch_bounds__(64) void head1_kernel(
    const float* __restrict__ x, const float* __restrict__ w,
    float* __restrict__ hmlp)
{
    const int n = blockIdx.x & 1023;
    const int b = blockIdx.x >> 10;
    const int t = threadIdx.x;
    const float4* cls = (const float4*)(x + (size_t)b * SEQ * 512);
    const float4* wr = (const float4*)(w + (size_t)n * 512);
    float s = 0.f;
#pragma unroll
    for (int i = 0; i < 2; ++i) {
        float4 a = cls[t + i * 64], c = wr[t + i * 64];
        s += a.x * c.x + a.y * c.y + a.z * c.z + a.w * c.w;
    }
#pragma unroll
    for (int o = 32; o; o >>= 1) s += __shfl_xor(s, o, 64);
    if (t == 0) hmlp[b * 1024 + n] = gelu_f(s);
}

__global__ __launch_bounds__(256) void head2_kernel(
    const float* __restrict__ hmlp, const float* __restrict__ w,
    float* __restrict__ out)
{
    __shared__ float red[4];
    const int b = blockIdx.x;
    const int t = threadIdx.x;
    float s = 0.f;
    for (int i = t; i < 1024; i += 256) s += hmlp[b * 1024 + i] * w[i];
#pragma unroll
    for (int o = 32; o; o >>= 1) s += __shfl_xor(s, o, 64);
    if ((t & 63) == 0) red[t >> 6] = s;
    __syncthreads();
    if (t == 0) out[b] = red[0] + red[1] + red[2] + red[3];
}

// ---------------------------------------------------------------------------
extern "C" void kernel_launch(void* const* d_in, const int* in_sizes, int n_in,
                              void* d_out, int out_size, void* d_ws, size_t ws_size,
                              hipStream_t stream)
{
    const float* feat_org = (const float*)d_in[0];
    const float* feat_r1  = (const float*)d_in[1];
    const float* feat_r2  = (const float*)d_in[2];
    const float* conv_w   = (const float*)d_in[3];
    const float* conv_b   = (const float*)d_in[4];
    const float* emb_org  = (const float*)d_in[5];
    const float* emb_r1   = (const float*)d_in[6];
    const float* emb_r2   = (const float*)d_in[7];
    const float* pos_emb  = (const float*)d_in[8];
    const float* cls_tok  = (const float*)d_in[9];
    const float* Wq = (const float*)d_in[10];
    const float* bq = (const float*)d_in[11];
    const float* Wk = (const float*)d_in[12];
    const float* bk = (const float*)d_in[13];
    const float* Wv = (const float*)d_in[14];
    const float* bv = (const float*)d_in[15];
    const float* Wo = (const float*)d_in[16];
    const float* bo = (const float*)d_in[17];
    const float* ln1g = (const float*)d_in[18];
    const float* ln1b = (const float*)d_in[19];
    const float* w1 = (const float*)d_in[20];
    const float* b1 = (const float*)d_in[21];
    const float* w2 = (const float*)d_in[22];
    const float* b2 = (const float*)d_in[23];
    const float* ln2g = (const float*)d_in[24];
    const float* ln2b = (const float*)d_in[25];
    const float* pw1 = (const float*)d_in[26];
    const float* pw2 = (const float*)d_in[27];
    const int*   mask = (const int*)d_in[28];

    float* ws = (float*)d_ws;
    // workspace layout (floats)
    float* ffh   = ws;                     // 7296*2048 = 14,942,208 (also patch)
    float* patch = ws;                     // 7288*2048 fits in ffh region
    float* x     = ws + 14942208;          // 7296*512
    float* qb_   = x + 3735552;
    float* kb_   = qb_ + 3735552;
    float* vb_   = kb_ + 3735552;
    float* ctx   = vb_ + 3735552;
    float* hmlp  = ctx + 3735552;          // 8192

    dim3 tb(32, 8);
    hipLaunchKernelGGL(transpose_feat_kernel, dim3(24, 64, 8), tb, 0, stream,
                       feat_org, patch, 768, 0);
    hipLaunchKernelGGL(transpose_feat_kernel, dim3(4, 64, 8), tb, 0, stream,
                       feat_r1, patch, 108, 768);
    hipLaunchKernelGGL(transpose_feat_kernel, dim3(2, 64, 8), tb, 0, stream,
                       feat_r2, patch, 35, 876);

    // embed GEMM -> tok (stored in qb_)
    hipLaunchKernelGGL((gemm_nt<64, 128, 0>), dim3(4, 114), 256, 0, stream,
                       patch, conv_w, conv_b, qb_, 7288, 512, 2048);
    hipLaunchKernelGGL(build_x_kernel, dim3(7296), 128, 0, stream,
                       qb_, cls_tok, emb_org, emb_r1, emb_r2, pos_emb, x);

    for (int l = 0; l < NLAYER; ++l) {
        const float* Wq_l = Wq + (size_t)l * 512 * 512;
        const float* Wk_l = Wk + (size_t)l * 512 * 512;
        const float* Wv_l = Wv + (size_t)l * 512 * 512;
        const float* Wo_l = Wo + (size_t)l * 512 * 512;
        const float* w1_l = w1 + (size_t)l * 2048 * 512;
        const float* w2_l = w2 + (size_t)l * 512 * 2048;

        hipLaunchKernelGGL((gemm_nt<64, 128, 0>), dim3(4, 114), 256, 0, stream,
                           x, Wq_l, bq + l * 512, qb_, 7296, 512, 512);
        hipLaunchKernelGGL((gemm_nt<64, 128, 0>), dim3(4, 114), 256, 0, stream,
                           x, Wk_l, bk + l * 512, kb_, 7296, 512, 512);
        hipLaunchKernelGGL((gemm_nt<64, 128, 0>), dim3(4, 114), 256, 0, stream,
                           x, Wv_l, bv + l * 512, vb_, 7296, 512, 512);
        hipLaunchKernelGGL(attn_flash, dim3(15, 8, 8), 256, 0, stream,
                           qb_, kb_, vb_, mask, ctx);
        hipLaunchKernelGGL((gemm_nt<64, 128, 0>), dim3(4, 114), 256, 0, stream,
                           ctx, Wo_l, bo + l * 512, qb_, 7296, 512, 512);
        hipLaunchKernelGGL(ln_residual_kernel, dim3(7296), 64, 0, stream,
                           x, qb_, ln1g + l * 512, ln1b + l * 512);
        hipLaunchKernelGGL((gemm_nt<128, 128, 1>), dim3(16, 57), 256, 0, stream,
                           x, w1_l, b1 + l * 2048, ffh, 7296, 2048, 512);
        hipLaunchKernelGGL((gemm_nt<64, 128, 0>), dim3(4, 114), 256, 0, stream,
                           ffh, w2_l, b2 + l * 512, qb_, 7296, 512, 2048);
        hipLaunchKernelGGL(ln_residual_kernel, dim3(7296), 64, 0, stream,
                           x, qb_, ln2g + l * 512, ln2b + l * 512);
    }

    hipLaunchKernelGGL(head1_kernel, dim3(8 * 1024), 64, 0, stream, x, pw1, hmlp);
    hipLaunchKernelGGL(head2_kernel, dim3(8), 256, 0, stream, hmlp, pw2, (float*)d_out);
}

// Round 3
// 3682.972 us; speedup vs baseline: 3.7160x; 1.8423x over previous
//
#include <hip/hip_runtime.h>
#include <hip/hip_bf16.h>
#include <math.h>

#define SEQ 912
#define NTOK 911
#define CIN_ 2048
#define NLAYER 6

typedef _Float16 f16x8 __attribute__((ext_vector_type(8)));
typedef _Float16 f16x4 __attribute__((ext_vector_type(4)));
typedef float f32x4 __attribute__((ext_vector_type(4)));

__device__ __forceinline__ float gelu_f(float x) {
    return 0.5f * x * (1.0f + erff(x * 0.70710678118654752f));
}

// ---------------------------------------------------------------------------
// fp16 MFMA NT GEMM: C[m,n] = sum_k A[m,k]*B[n,k] + bias[n]
// A: (M,K) fp16 row-major, B: (N,K) fp16 row-major. bias fp32.
// 256 thr = 4 waves; block tile 128x128, wave tile 64x64 (4x4 mfma frags).
// LDS rows padded to 40 halves (80B): 16B-aligned b128 reads, 2-way banks.
// ---------------------------------------------------------------------------
template <int ACT, int OUT16>
__global__ __launch_bounds__(256) void gemm16(
    const _Float16* __restrict__ A, const _Float16* __restrict__ B,
    const float* __restrict__ bias, void* __restrict__ Cout,
    int M, int N, int K)
{
    constexpr int BK = 32;
    __shared__ __align__(16) _Float16 As[128 * 40];
    __shared__ __align__(16) _Float16 Bs[128 * 40];
    const int t = threadIdx.x;
    const int m0 = blockIdx.y * 128, n0 = blockIdx.x * 128;
    const int lane = t & 63, w = t >> 6;
    const int r0 = (w >> 1) * 64, c0 = (w & 1) * 64;
    const int ln15 = lane & 15, quad = lane >> 4;
    const int srow = t >> 2, schunk = (t & 3) * 8;

    f32x4 zero = {0.f, 0.f, 0.f, 0.f};
    f32x4 acc[4][4];
#pragma unroll
    for (int i = 0; i < 4; ++i)
#pragma unroll
        for (int j = 0; j < 4; ++j) acc[i][j] = zero;

    for (int k0 = 0; k0 < K; k0 += BK) {
#pragma unroll
        for (int p = 0; p < 2; ++p) {
            int m = p * 64 + srow;
            int gm = m0 + m;
            float4 av = make_float4(0.f, 0.f, 0.f, 0.f);
            if (gm < M) av = *(const float4*)(A + (size_t)gm * K + k0 + schunk);
            *(float4*)&As[m * 40 + schunk] = av;
            int gn = n0 + m;
            float4 bv = make_float4(0.f, 0.f, 0.f, 0.f);
            if (gn < N) bv = *(const float4*)(B + (size_t)gn * K + k0 + schunk);
            *(float4*)&Bs[m * 40 + schunk] = bv;
        }
        __syncthreads();
        f16x8 a[4], b[4];
#pragma unroll
        for (int i = 0; i < 4; ++i)
            a[i] = *(const f16x8*)&As[(r0 + i * 16 + ln15) * 40 + quad * 8];
#pragma unroll
        for (int j = 0; j < 4; ++j)
            b[j] = *(const f16x8*)&Bs[(c0 + j * 16 + ln15) * 40 + quad * 8];
#pragma unroll
        for (int i = 0; i < 4; ++i)
#pragma unroll
            for (int j = 0; j < 4; ++j)
                acc[i][j] = __builtin_amdgcn_mfma_f32_16x16x32_f16(a[i], b[j], acc[i][j], 0, 0, 0);
        __syncthreads();
    }

#pragma unroll
    for (int j = 0; j < 4; ++j) {
        int gn = n0 + c0 + j * 16 + ln15;
        float bv = bias[gn];
#pragma unroll
        for (int i = 0; i < 4; ++i) {
            int gmBase = m0 + r0 + i * 16 + quad * 4;
#pragma unroll
            for (int r = 0; r < 4; ++r) {
                int gm = gmBase + r;
                if (gm >= M) continue;
                float val = acc[i][j][r] + bv;
                if (ACT == 1) val = gelu_f(val);
                if (OUT16) ((_Float16*)Cout)[(size_t)gm * N + gn] = (_Float16)val;
                else       ((float*)Cout)[(size_t)gm * N + gn] = val;
            }
        }
    }
}

// ---------------------------------------------------------------------------
// cast fp32 -> fp16, 4 elems/thread (n must be multiple of 4)
// ---------------------------------------------------------------------------
__global__ __launch_bounds__(256) void cast16_kernel(
    const float* __restrict__ src, _Float16* __restrict__ dst, int n4)
{
    int i = blockIdx.x * 256 + threadIdx.x;
    if (i < n4) {
        float4 v = ((const float4*)src)[i];
        f16x4 h;
        h[0] = (_Float16)v.x; h[1] = (_Float16)v.y;
        h[2] = (_Float16)v.z; h[3] = (_Float16)v.w;
        ((f16x4*)dst)[i] = h;
    }
}

// ---------------------------------------------------------------------------
// Transpose feat (B,CIN,H,W) -> fp16 patch rows (b*911 + tok_off + p, CIN)
// ---------------------------------------------------------------------------
__global__ __launch_bounds__(256) void transpose_feat_kernel(
    const float* __restrict__ feat, _Float16* __restrict__ patch, int HW, int tok_off)
{
    __shared__ float tile[32][33];
    const int b = blockIdx.z;
    const int c0 = blockIdx.y * 32;
    const int p0 = blockIdx.x * 32;
    const int tx = threadIdx.x, ty = threadIdx.y;
#pragma unroll
    for (int i = 0; i < 4; ++i) {
        int c = c0 + ty + i * 8;
        int p = p0 + tx;
        tile[ty + i * 8][tx] = (p < HW) ? feat[((size_t)b * CIN_ + c) * HW + p] : 0.f;
    }
    __syncthreads();
#pragma unroll
    for (int i = 0; i < 4; ++i) {
        int p = p0 + ty + i * 8;
        int c = c0 + tx;
        if (p < HW)
            patch[((size_t)(b * NTOK + tok_off + p)) * CIN_ + c] = (_Float16)tile[tx][ty + i * 8];
    }
}

// ---------------------------------------------------------------------------
// Assemble x (B,912,512) fp32: cls + tok + channel emb + pos emb
// ---------------------------------------------------------------------------
__global__ __launch_bounds__(128) void build_x_kernel(
    const float* __restrict__ tok, const float* __restrict__ cls_token,
    const float* __restrict__ emb_org, const float* __restrict__ emb_r1,
    const float* __restrict__ emb_r2, const float* __restrict__ pos_emb,
    float* __restrict__ x)
{
    const int row = blockIdx.x;
    const int b = row / SEQ;
    const int tt = row - b * SEQ;
    const int d4 = threadIdx.x;
    float4 o;
    if (tt == 0) {
        o = ((const float4*)cls_token)[d4];
    } else {
        int tp = tt - 1;
        const float* ce; int hh, ww, p;
        if (tp < 768)      { p = tp;       hh = 24; ww = 32; ce = emb_org; }
        else if (tp < 876) { p = tp - 768; hh = 9;  ww = 12; ce = emb_r1; }
        else               { p = tp - 876; hh = 5;  ww = 7;  ce = emb_r2; }
        int i = p / ww, j = p - i * ww;
        int ti = (i * 10) / hh, tj = (j * 10) / ww;
        float4 tv = ((const float4*)(tok + (size_t)(b * NTOK + tp) * 512))[d4];
        float4 cv = ((const float4*)ce)[d4];
        float4 pv = ((const float4*)(pos_emb + (size_t)(ti * 10 + tj) * 512))[d4];
        o.x = tv.x + cv.x + pv.x; o.y = tv.y + cv.y + pv.y;
        o.z = tv.z + cv.z + pv.z; o.w = tv.w + cv.w + pv.w;
    }
    ((float4*)(x + (size_t)row * 512))[d4] = o;
}

// ---------------------------------------------------------------------------
// Flash attention, fp32 math, fp16 qkv input (fused layout, ld=1536),
// fp16 ctx output (ld=512).
// ---------------------------------------------------------------------------
__global__ __launch_bounds__(256) void attn_flash(
    const _Float16* __restrict__ qkv, const int* __restrict__ mask,
    _Float16* __restrict__ ctx)
{
    constexpr int P = 68;
    constexpr int LD = 1536;
    __shared__ __align__(16) float qsT[64][P];   // [d][row], pre-scaled
    __shared__ __align__(16) float kv[64][P];    // K: [d][col]; V: [key][d]
    __shared__ __align__(16) float psT[64][P];   // [key][row]
    const int qt = blockIdx.x, h = blockIdx.y, b = blockIdx.z;
    const int q0 = qt * 64;
    const int t = threadIdx.x;
    const int tx4 = (t & 15) * 4;
    const int ty4 = (t >> 4) * 4;

    // load Q transposed, scaled (64 rows x 64 cols, 8 halves per thread-iter)
#pragma unroll
    for (int it = 0; it < 2; ++it) {
        int flat = t + it * 256;
        int r = flat >> 3;
        int ch = (flat & 7) * 8;
        int gq = q0 + r;
        if (gq < SEQ) {
            f16x8 hv = *(const f16x8*)(qkv + (size_t)(b * SEQ + gq) * LD + h * 64 + ch);
#pragma unroll
            for (int u = 0; u < 8; ++u) qsT[ch + u][r] = (float)hv[u] * 0.125f;
        } else {
#pragma unroll
            for (int u = 0; u < 8; ++u) qsT[ch + u][r] = 0.f;
        }
    }

    float m_i[4], l_i[4], o[4][4];
#pragma unroll
    for (int i = 0; i < 4; ++i) {
        m_i[i] = -1e30f; l_i[i] = 0.f;
#pragma unroll
        for (int j = 0; j < 4; ++j) o[i][j] = 0.f;
    }

    for (int kb = 0; kb < 960; kb += 64) {
        __syncthreads();
#pragma unroll
        for (int it = 0; it < 2; ++it) {
            int flat = t + it * 256;
            int r = flat >> 3;
            int ch = (flat & 7) * 8;
            int kg = kb + r;
            if (kg < SEQ) {
                f16x8 hv = *(const f16x8*)(qkv + (size_t)(b * SEQ + kg) * LD + 512 + h * 64 + ch);
#pragma unroll
                for (int u = 0; u < 8; ++u) kv[ch + u][r] = (float)hv[u];
            } else {
#pragma unroll
                for (int u = 0; u < 8; ++u) kv[ch + u][r] = 0.f;
            }
        }
        __syncthreads();

        float s[4][4];
#pragma unroll
        for (int i = 0; i < 4; ++i)
#pragma unroll
            for (int j = 0; j < 4; ++j) s[i][j] = 0.f;
#pragma unroll 16
        for (int d = 0; d < 64; ++d) {
            float4 qv = *(const float4*)&qsT[d][ty4];
            float4 kk_ = *(const float4*)&kv[d][tx4];
            float qa[4] = {qv.x, qv.y, qv.z, qv.w};
            float ka[4] = {kk_.x, kk_.y, kk_.z, kk_.w};
#pragma unroll
            for (int i = 0; i < 4; ++i)
#pragma unroll
                for (int j = 0; j < 4; ++j)
                    s[i][j] = fmaf(qa[i], ka[j], s[i][j]);
        }

        float bias[4];
#pragma unroll
        for (int j = 0; j < 4; ++j) {
            int kg = kb + tx4 + j;
            bias[j] = (kg < SEQ) ? (mask[b * SEQ + kg] ? 0.f : -1e9f) : -2e9f;
        }

#pragma unroll
        for (int i = 0; i < 4; ++i) {
            float mx = -3e38f;
#pragma unroll
            for (int j = 0; j < 4; ++j) { s[i][j] += bias[j]; mx = fmaxf(mx, s[i][j]); }
            mx = fmaxf(mx, __shfl_xor(mx, 1, 64));
            mx = fmaxf(mx, __shfl_xor(mx, 2, 64));
            mx = fmaxf(mx, __shfl_xor(mx, 4, 64));
            mx = fmaxf(mx, __shfl_xor(mx, 8, 64));
            float mnew = fmaxf(m_i[i], mx);
            float alpha = __expf(m_i[i] - mnew);
            m_i[i] = mnew;
            float sum = 0.f;
#pragma unroll
            for (int j = 0; j < 4; ++j) {
                s[i][j] = __expf(s[i][j] - mnew);
                sum += s[i][j];
            }
            sum += __shfl_xor(sum, 1, 64);
            sum += __shfl_xor(sum, 2, 64);
            sum += __shfl_xor(sum, 4, 64);
            sum += __shfl_xor(sum, 8, 64);
            l_i[i] = l_i[i] * alpha + sum;
#pragma unroll
            for (int j = 0; j < 4; ++j) o[i][j] *= alpha;
        }

#pragma unroll
        for (int j = 0; j < 4; ++j) {
            float4 pv = make_float4(s[0][j], s[1][j], s[2][j], s[3][j]);
            *(float4*)&psT[tx4 + j][ty4] = pv;
        }
        __syncthreads();

#pragma unroll
        for (int it = 0; it < 2; ++it) {
            int flat = t + it * 256;
            int r = flat >> 3;
            int ch = (flat & 7) * 8;
            int kg = kb + r;
            if (kg < SEQ) {
                f16x8 hv = *(const f16x8*)(qkv + (size_t)(b * SEQ + kg) * LD + 1024 + h * 64 + ch);
#pragma unroll
                for (int u = 0; u < 8; ++u) kv[r][ch + u] = (float)hv[u];
            } else {
#pragma unroll
                for (int u = 0; u < 8; ++u) kv[r][ch + u] = 0.f;
            }
        }
        __syncthreads();

#pragma unroll 16
        for (int kk = 0; kk < 64; ++kk) {
            float4 pp = *(const float4*)&psT[kk][ty4];
            float4 vv = *(const float4*)&kv[kk][tx4];
            float pa[4] = {pp.x, pp.y, pp.z, pp.w};
            float va[4] = {vv.x, vv.y, vv.z, vv.w};
#pragma unroll
            for (int i = 0; i < 4; ++i)
#pragma unroll
                for (int j = 0; j < 4; ++j)
                    o[i][j] = fmaf(pa[i], va[j], o[i][j]);
        }
    }

#pragma unroll
    for (int i = 0; i < 4; ++i) {
        int row = q0 + ty4 + i;
        if (row < SEQ) {
            float inv = 1.f / l_i[i];
            _Float16* cp = ctx + (size_t)(b * SEQ + row) * 512 + h * 64 + tx4;
#pragma unroll
            for (int j = 0; j < 4; ++j) cp[j] = (_Float16)(o[i][j] * inv);
        }
    }
}

// ---------------------------------------------------------------------------
// x = LN(x + r) * g + beta, one wave per 512-wide row
// ---------------------------------------------------------------------------
__global__ __launch_bounds__(64) void ln_residual_kernel(
    float* __restrict__ x, const float* __restrict__ r,
    const float* __restrict__ g, const float* __restrict__ bta)
{
    const int row = blockIdx.x;
    const int t = threadIdx.x;
    float4* xr = (float4*)(x + (size_t)row * 512);
    const float4* rr = (const float4*)(r + (size_t)row * 512);
    float4 a0 = xr[t], a1 = xr[t + 64];
    float4 b0 = rr[t], b1 = rr[t + 64];
    a0.x += b0.x; a0.y += b0.y; a0.z += b0.z; a0.w += b0.w;
    a1.x += b1.x; a1.y += b1.y; a1.z += b1.z; a1.w += b1.w;
    float s = a0.x + a0.y + a0.z + a0.w + a1.x + a1.y + a1.z + a1.w;
#pragma unroll
    for (int o = 32; o; o >>= 1) s += __shfl_xor(s, o, 64);
    const float mean = s * (1.f / 512.f);
    float sq = 0.f;
    sq += (a0.x - mean) * (a0.x - mean); sq += (a0.y - mean) * (a0.y - mean);
    sq += (a0.z - mean) * (a0.z - mean); sq += (a0.w - mean) * (a0.w - mean);
    sq += (a1.x - mean) * (a1.x - mean); sq += (a1.y - mean) * (a1.y - mean);
    sq += (a1.z - mean) * (a1.z - mean); sq += (a1.w - mean) * (a1.w - mean);
#pragma unroll
    for (int o = 32; o; o >>= 1) sq += __shfl_xor(sq, o, 64);
    const float rstd = rsqrtf(sq * (1.f / 512.f) + 1e-6f);
    const float4 g0 = ((const float4*)g)[t], g1 = ((const float4*)g)[t + 64];
    const float4 e0 = ((const float4*)bta)[t], e1 = ((const float4*)bta)[t + 64];
    float4 o0, o1;
    o0.x = (a0.x - mean) * rstd * g0.x + e0.x;
    o0.y = (a0.y - mean) * rstd * g0.y + e0.y;
    o0.z = (a0.z - mean) * rstd * g0.z + e0.z;
    o0.w = (a0.w - mean) * rstd * g0.w + e0.w;
    o1.x = (a1.x - mean) * rstd * g1.x + e1.x;
    o1.y = (a1.y - mean) * rstd * g1.y + e1.y;
    o1.z = (a1.z - mean) * rstd * g1.z + e1.z;
    o1.w = (a1.w - mean) * rstd * g1.w + e1.w;
    xr[t] = o0; xr[t + 64] = o1;
}

// ---------------------------------------------------------------------------
// Head (fp32, tiny)
// ---------------------------------------------------------------------------
__global__ __launch_bounds__(64) void head1_kernel(
    const float* __restrict__ x, const float* __restrict__ w,
    float* __restrict__ hmlp)
{
    const int n = blockIdx.x & 1023;
    const int b = blockIdx.x >> 10;
    const int t = threadIdx.x;
    const float4* cls = (const float4*)(x + (size_t)b * SEQ * 512);
    const float4* wr = (const float4*)(w + (size_t)n * 512);
    float s = 0.f;
#pragma unroll
    for (int i = 0; i < 2; ++i) {
        float4 a = cls[t + i * 64], c = wr[t + i * 64];
        s += a.x * c.x + a.y * c.y + a.z * c.z + a.w * c.w;
    }
#pragma unroll
    for (int o = 32; o; o >>= 1) s += __shfl_xor(s, o, 64);
    if (t == 0) hmlp[b * 1024 + n] = gelu_f(s);
}

__global__ __launch_bounds__(256) void head2_kernel(
    const float* __restrict__ hmlp, const float* __restrict__ w,
    float* __restrict__ out)
{
    __shared__ float red[4];
    const int b = blockIdx.x;
    const int t = threadIdx.x;
    float s = 0.f;
    for (int i = t; i < 1024; i += 256) s += hmlp[b * 1024 + i] * w[i];
#pragma unroll
    for (int o = 32; o; o >>= 1) s += __shfl_xor(s, o, 64);
    if ((t & 63) == 0) red[t >> 6] = s;
    __syncthreads();
    if (t == 0) out[b] = red[0] + red[1] + red[2] + red[3];
}

// ---------------------------------------------------------------------------
static inline void cast16(const float* s, _Float16* d, long n, hipStream_t st) {
    long n4 = n / 4;
    hipLaunchKernelGGL(cast16_kernel, dim3((n4 + 255) / 256), 256, 0, st, s, d, (int)n4);
}

extern "C" void kernel_launch(void* const* d_in, const int* in_sizes, int n_in,
                              void* d_out, int out_size, void* d_ws, size_t ws_size,
                              hipStream_t stream)
{
    const float* feat_org = (const float*)d_in[0];
    const float* feat_r1  = (const float*)d_in[1];
    const float* feat_r2  = (const float*)d_in[2];
    const float* conv_w   = (const float*)d_in[3];
    const float* conv_b   = (const float*)d_in[4];
    const float* emb_org  = (const float*)d_in[5];
    const float* emb_r1   = (const float*)d_in[6];
    const float* emb_r2   = (const float*)d_in[7];
    const float* pos_emb  = (const float*)d_in[8];
    const float* cls_tok  = (const float*)d_in[9];
    const float* Wq = (const float*)d_in[10];
    const float* bq = (const float*)d_in[11];
    const float* Wk = (const float*)d_in[12];
    const float* bk = (const float*)d_in[13];
    const float* Wv = (const float*)d_in[14];
    const float* bv = (const float*)d_in[15];
    const float* Wo = (const float*)d_in[16];
    const float* bo = (const float*)d_in[17];
    const float* ln1g = (const float*)d_in[18];
    const float* ln1b = (const float*)d_in[19];
    const float* w1 = (const float*)d_in[20];
    const float* b1 = (const float*)d_in[21];
    const float* w2 = (const float*)d_in[22];
    const float* b2 = (const float*)d_in[23];
    const float* ln2g = (const float*)d_in[24];
    const float* ln2b = (const float*)d_in[25];
    const float* pw1 = (const float*)d_in[26];
    const float* pw2 = (const float*)d_in[27];
    const int*   mask = (const int*)d_in[28];

    // -------- workspace layout (bytes) --------
    char* base = (char*)d_ws;
    _Float16* ffh16  = (_Float16*)base;                 // 7296*2048 f16 (also patch16)
    _Float16* patch16 = ffh16;
    base += (size_t)7296 * 2048 * 2;                    // 29,884,416
    float* x   = (float*)base; base += (size_t)7296 * 512 * 4;   // 14,942,208
    float* att = (float*)base; base += (size_t)7296 * 512 * 4;   // also tok (embed out)
    float* tok = att;
    _Float16* qkv16 = (_Float16*)base; base += (size_t)7296 * 1536 * 2; // 22,413,312
    _Float16* x16   = (_Float16*)base; base += (size_t)7296 * 512 * 2;
    _Float16* ctx16 = (_Float16*)base; base += (size_t)7296 * 512 * 2;
    _Float16* wqkv16 = (_Float16*)base; base += (size_t)1536 * 512 * 2;
    _Float16* wo16   = (_Float16*)base; base += (size_t)512 * 512 * 2;
    _Float16* w1_16  = (_Float16*)base; base += (size_t)2048 * 512 * 2;
    _Float16* w2_16  = (_Float16*)base; base += (size_t)512 * 2048 * 2;
    _Float16* convw16 = (_Float16*)base; base += (size_t)512 * 2048 * 2;
    float* bqkv = (float*)base; base += 1536 * 4;
    float* hmlp = (float*)base; base += 8 * 1024 * 4;

    dim3 tb(32, 8);
    hipLaunchKernelGGL(transpose_feat_kernel, dim3(24, 64, 8), tb, 0, stream,
                       feat_org, patch16, 768, 0);
    hipLaunchKernelGGL(transpose_feat_kernel, dim3(4, 64, 8), tb, 0, stream,
                       feat_r1, patch16, 108, 768);
    hipLaunchKernelGGL(transpose_feat_kernel, dim3(2, 64, 8), tb, 0, stream,
                       feat_r2, patch16, 35, 876);
    cast16(conv_w, convw16, (long)512 * 2048, stream);

    // embed GEMM: (7288,2048)x(512,2048)^T -> tok fp32
    hipLaunchKernelGGL((gemm16<0, 0>), dim3(4, 57), 256, 0, stream,
                       patch16, convw16, conv_b, (void*)tok, 7288, 512, 2048);
    hipLaunchKernelGGL(build_x_kernel, dim3(7296), 128, 0, stream,
                       tok, cls_tok, emb_org, emb_r1, emb_r2, pos_emb, x);

    for (int l = 0; l < NLAYER; ++l) {
        const size_t lw = (size_t)l * 512 * 512;
        // weight prep
        cast16(Wq + lw, wqkv16, 512 * 512, stream);
        cast16(Wk + lw, wqkv16 + 512 * 512, 512 * 512, stream);
        cast16(Wv + lw, wqkv16 + 1024 * 512, 512 * 512, stream);
        hipMemcpyAsync(bqkv,        bq + l * 512, 512 * 4, hipMemcpyDeviceToDevice, stream);
        hipMemcpyAsync(bqkv + 512,  bk + l * 512, 512 * 4, hipMemcpyDeviceToDevice, stream);
        hipMemcpyAsync(bqkv + 1024, bv + l * 512, 512 * 4, hipMemcpyDeviceToDevice, stream);

        cast16(x, x16, (long)7296 * 512, stream);
        hipLaunchKernelGGL((gemm16<0, 1>), dim3(12, 57), 256, 0, stream,
                           x16, wqkv16, bqkv, (void*)qkv16, 7296, 1536, 512);
        hipLaunchKernelGGL(attn_flash, dim3(15, 8, 8), 256, 0, stream,
                           qkv16, mask, ctx16);
        cast16(Wo + lw, wo16, 512 * 512, stream);
        hipLaunchKernelGGL((gemm16<0, 0>), dim3(4, 57), 256, 0, stream,
                           ctx16, wo16, bo + l * 512, (void*)att, 7296, 512, 512);
        hipLaunchKernelGGL(ln_residual_kernel, dim3(7296), 64, 0, stream,
                           x, att, ln1g + l * 512, ln1b + l * 512);

        cast16(w1 + (size_t)l * 2048 * 512, w1_16, (long)2048 * 512, stream);
        cast16(x, x16, (long)7296 * 512, stream);
        hipLaunchKernelGGL((gemm16<1, 1>), dim3(16, 57), 256, 0, stream,
                           x16, w1_16, b1 + l * 2048, (void*)ffh16, 7296, 2048, 512);
        cast16(w2 + (size_t)l * 512 * 2048, w2_16, (long)512 * 2048, stream);
        hipLaunchKernelGGL((gemm16<0, 0>), dim3(4, 57), 256, 0, stream,
                           ffh16, w2_16, b2 + l * 512, (void*)att, 7296, 512, 2048);
        hipLaunchKernelGGL(ln_residual_kernel, dim3(7296), 64, 0, stream,
                           x, att, ln2g + l * 512, ln2b + l * 512);
    }

    hipLaunchKernelGGL(head1_kernel, dim3(8 * 1024), 64, 0, stream, x, pw1, hmlp);
    hipLaunchKernelGGL(head2_kernel, dim3(8), 256, 0, stream, hmlp, pw2, (float*)d_out);
}

// Round 4
// 2151.182 us; speedup vs baseline: 6.3621x; 1.7121x over previous
//
#include <hip/hip_runtime.h>
#include <hip/hip_bf16.h>
#include <math.h>

#define SEQ 912
#define NTOK 911
#define CIN_ 2048
#define NLAYER 6

typedef _Float16 f16x8 __attribute__((ext_vector_type(8)));
typedef _Float16 f16x4 __attribute__((ext_vector_type(4)));
typedef float f32x4 __attribute__((ext_vector_type(4)));

__device__ __forceinline__ float gelu_f(float x) {
    return 0.5f * x * (1.0f + erff(x * 0.70710678118654752f));
}

// ---------------------------------------------------------------------------
// fp16 MFMA NT GEMM: C[m,n] = sum_k A[m,k]*B[n,k] + bias[n]
// ---------------------------------------------------------------------------
template <int ACT, int OUT16>
__global__ __launch_bounds__(256) void gemm16(
    const _Float16* __restrict__ A, const _Float16* __restrict__ B,
    const float* __restrict__ bias, void* __restrict__ Cout,
    int M, int N, int K)
{
    constexpr int BK = 32;
    __shared__ __align__(16) _Float16 As[128 * 40];
    __shared__ __align__(16) _Float16 Bs[128 * 40];
    const int t = threadIdx.x;
    const int m0 = blockIdx.y * 128, n0 = blockIdx.x * 128;
    const int lane = t & 63, w = t >> 6;
    const int r0 = (w >> 1) * 64, c0 = (w & 1) * 64;
    const int ln15 = lane & 15, quad = lane >> 4;
    const int srow = t >> 2, schunk = (t & 3) * 8;

    f32x4 zero = {0.f, 0.f, 0.f, 0.f};
    f32x4 acc[4][4];
#pragma unroll
    for (int i = 0; i < 4; ++i)
#pragma unroll
        for (int j = 0; j < 4; ++j) acc[i][j] = zero;

    for (int k0 = 0; k0 < K; k0 += BK) {
#pragma unroll
        for (int p = 0; p < 2; ++p) {
            int m = p * 64 + srow;
            int gm = m0 + m;
            float4 av = make_float4(0.f, 0.f, 0.f, 0.f);
            if (gm < M) av = *(const float4*)(A + (size_t)gm * K + k0 + schunk);
            *(float4*)&As[m * 40 + schunk] = av;
            int gn = n0 + m;
            float4 bv = make_float4(0.f, 0.f, 0.f, 0.f);
            if (gn < N) bv = *(const float4*)(B + (size_t)gn * K + k0 + schunk);
            *(float4*)&Bs[m * 40 + schunk] = bv;
        }
        __syncthreads();
        f16x8 a[4], b[4];
#pragma unroll
        for (int i = 0; i < 4; ++i)
            a[i] = *(const f16x8*)&As[(r0 + i * 16 + ln15) * 40 + quad * 8];
#pragma unroll
        for (int j = 0; j < 4; ++j)
            b[j] = *(const f16x8*)&Bs[(c0 + j * 16 + ln15) * 40 + quad * 8];
#pragma unroll
        for (int i = 0; i < 4; ++i)
#pragma unroll
            for (int j = 0; j < 4; ++j)
                acc[i][j] = __builtin_amdgcn_mfma_f32_16x16x32_f16(a[i], b[j], acc[i][j], 0, 0, 0);
        __syncthreads();
    }

#pragma unroll
    for (int j = 0; j < 4; ++j) {
        int gn = n0 + c0 + j * 16 + ln15;
        float bv = bias[gn];
#pragma unroll
        for (int i = 0; i < 4; ++i) {
            int gmBase = m0 + r0 + i * 16 + quad * 4;
#pragma unroll
            for (int r = 0; r < 4; ++r) {
                int gm = gmBase + r;
                if (gm >= M) continue;
                float val = acc[i][j][r] + bv;
                if (ACT == 1) val = gelu_f(val);
                if (OUT16) ((_Float16*)Cout)[(size_t)gm * N + gn] = (_Float16)val;
                else       ((float*)Cout)[(size_t)gm * N + gn] = val;
            }
        }
    }
}

// ---------------------------------------------------------------------------
// cast fp32 -> fp16
// ---------------------------------------------------------------------------
__global__ __launch_bounds__(256) void cast16_kernel(
    const float* __restrict__ src, _Float16* __restrict__ dst, int n4)
{
    int i = blockIdx.x * 256 + threadIdx.x;
    if (i < n4) {
        float4 v = ((const float4*)src)[i];
        f16x4 h;
        h[0] = (_Float16)v.x; h[1] = (_Float16)v.y;
        h[2] = (_Float16)v.z; h[3] = (_Float16)v.w;
        ((f16x4*)dst)[i] = h;
    }
}

// ---------------------------------------------------------------------------
// Transpose feat (B,CIN,H,W) -> fp16 patch rows
// ---------------------------------------------------------------------------
__global__ __launch_bounds__(256) void transpose_feat_kernel(
    const float* __restrict__ feat, _Float16* __restrict__ patch, int HW, int tok_off)
{
    __shared__ float tile[32][33];
    const int b = blockIdx.z;
    const int c0 = blockIdx.y * 32;
    const int p0 = blockIdx.x * 32;
    const int tx = threadIdx.x, ty = threadIdx.y;
#pragma unroll
    for (int i = 0; i < 4; ++i) {
        int c = c0 + ty + i * 8;
        int p = p0 + tx;
        tile[ty + i * 8][tx] = (p < HW) ? feat[((size_t)b * CIN_ + c) * HW + p] : 0.f;
    }
    __syncthreads();
#pragma unroll
    for (int i = 0; i < 4; ++i) {
        int p = p0 + ty + i * 8;
        int c = c0 + tx;
        if (p < HW)
            patch[((size_t)(b * NTOK + tok_off + p)) * CIN_ + c] = (_Float16)tile[tx][ty + i * 8];
    }
}

// ---------------------------------------------------------------------------
// Assemble x (B,912,512) fp32
// ---------------------------------------------------------------------------
__global__ __launch_bounds__(128) void build_x_kernel(
    const float* __restrict__ tok, const float* __restrict__ cls_token,
    const float* __restrict__ emb_org, const float* __restrict__ emb_r1,
    const float* __restrict__ emb_r2, const float* __restrict__ pos_emb,
    float* __restrict__ x)
{
    const int row = blockIdx.x;
    const int b = row / SEQ;
    const int tt = row - b * SEQ;
    const int d4 = threadIdx.x;
    float4 o;
    if (tt == 0) {
        o = ((const float4*)cls_token)[d4];
    } else {
        int tp = tt - 1;
        const float* ce; int hh, ww, p;
        if (tp < 768)      { p = tp;       hh = 24; ww = 32; ce = emb_org; }
        else if (tp < 876) { p = tp - 768; hh = 9;  ww = 12; ce = emb_r1; }
        else               { p = tp - 876; hh = 5;  ww = 7;  ce = emb_r2; }
        int i = p / ww, j = p - i * ww;
        int ti = (i * 10) / hh, tj = (j * 10) / ww;
        float4 tv = ((const float4*)(tok + (size_t)(b * NTOK + tp) * 512))[d4];
        float4 cv = ((const float4*)ce)[d4];
        float4 pv = ((const float4*)(pos_emb + (size_t)(ti * 10 + tj) * 512))[d4];
        o.x = tv.x + cv.x + pv.x; o.y = tv.y + cv.y + pv.y;
        o.z = tv.z + cv.z + pv.z; o.w = tv.w + cv.w + pv.w;
    }
    ((float4*)(x + (size_t)row * 512))[d4] = o;
}

// ---------------------------------------------------------------------------
// V^T builder: qkv V-section (b,s,h,d) -> vT[(b*8+h)*64 + d][960 keys] fp16
// Keys >= SEQ zero-filled. LDS 68-half stride: conflict-free column reads.
// ---------------------------------------------------------------------------
__global__ __launch_bounds__(256) void vtrans_kernel(
    const _Float16* __restrict__ qkv, _Float16* __restrict__ vT)
{
    __shared__ _Float16 Ls[64 * 68];
    const int kb = blockIdx.x * 64, h = blockIdx.y, b = blockIdx.z;
    const int t = threadIdx.x;
#pragma unroll
    for (int i = 0; i < 2; ++i) {
        int u = t + i * 256;
        int r = u >> 3, ch = (u & 7) * 8;
        int kg = kb + r;
        f16x8 v = {0, 0, 0, 0, 0, 0, 0, 0};
        if (kg < SEQ) v = *(const f16x8*)(qkv + (size_t)(b * SEQ + kg) * 1536 + 1024 + h * 64 + ch);
        f16x4 lo = {v[0], v[1], v[2], v[3]}, hi = {v[4], v[5], v[6], v[7]};
        *(f16x4*)&Ls[r * 68 + ch] = lo;
        *(f16x4*)&Ls[r * 68 + ch + 4] = hi;
    }
    __syncthreads();
#pragma unroll
    for (int i = 0; i < 2; ++i) {
        int u = t + i * 256;
        int d = u & 63, kc = (u >> 6) * 8;
        f16x8 o;
#pragma unroll
        for (int j = 0; j < 8; ++j) o[j] = Ls[(kc + j) * 68 + d];
        *(f16x8*)&vT[((size_t)((b * 8 + h) * 64 + d)) * 960 + kb + kc] = o;
    }
}

// ---------------------------------------------------------------------------
// MFMA flash attention. Block = (b,h,64 queries), 4 waves x 16 queries.
// S^T = K·Q^T: each lane owns one query's scores -> cheap softmax.
// P -> PV A-operand via wave-private LDS transpose. V^T tiles from vT global.
// ---------------------------------------------------------------------------
__global__ __launch_bounds__(256) void attn_mfma(
    const _Float16* __restrict__ qkv, const _Float16* __restrict__ vT,
    const int* __restrict__ mask, _Float16* __restrict__ ctx)
{
    __shared__ __align__(16) _Float16 Ks[64 * 72];
    __shared__ __align__(16) _Float16 VTs[64 * 72];
    __shared__ __align__(16) _Float16 Pw[4][16 * 72];
    __shared__ float biasS[64];
    const int qt = blockIdx.x, h = blockIdx.y, b = blockIdx.z;
    const int q0 = qt * 64;
    const int t = threadIdx.x;
    const int wave = t >> 6, lane = t & 63;
    const int ln15 = lane & 15, quad = lane >> 4;
    const int qrow = q0 + wave * 16 + ln15;

    // Q B-operand fragments (2 k-steps over d=64), contiguous from global
    f16x8 qf[2];
#pragma unroll
    for (int ks = 0; ks < 2; ++ks) {
        f16x8 z = {0, 0, 0, 0, 0, 0, 0, 0};
        qf[ks] = (qrow < SEQ)
            ? *(const f16x8*)(qkv + (size_t)(b * SEQ + qrow) * 1536 + h * 64 + ks * 32 + quad * 8)
            : z;
    }

    f32x4 oacc[4];
    f32x4 zero = {0.f, 0.f, 0.f, 0.f};
#pragma unroll
    for (int dj = 0; dj < 4; ++dj) oacc[dj] = zero;
    float m_i = -1e30f, l_i = 0.f;   // per lane: query = ln15 (dup across quads)

    for (int kb = 0; kb < 960; kb += 64) {
        // ---- stage K tile (natural) and V^T tile ----
#pragma unroll
        for (int i = 0; i < 2; ++i) {
            int u = t + i * 256;
            int r = u >> 3, ch = (u & 7) * 8;
            int kg = kb + r;
            f16x8 kvv = {0, 0, 0, 0, 0, 0, 0, 0};
            if (kg < SEQ) kvv = *(const f16x8*)(qkv + (size_t)(b * SEQ + kg) * 1536 + 512 + h * 64 + ch);
            *(f16x8*)&Ks[r * 72 + ch] = kvv;
            f16x8 vv = *(const f16x8*)(vT + ((size_t)((b * 8 + h) * 64 + r)) * 960 + kb + ch);
            *(f16x8*)&VTs[r * 72 + ch] = vv;
        }
        if (t < 64) {
            int kg = kb + t;
            biasS[t] = (kg < SEQ) ? (mask[b * SEQ + kg] ? 0.f : -1e9f) : -2e9f;
        }
        __syncthreads();

        // ---- S^T = K·Q^T : 4 key-groups x 2 k-steps ----
        f32x4 st[4];
#pragma unroll
        for (int jj = 0; jj < 4; ++jj) st[jj] = zero;
#pragma unroll
        for (int jj = 0; jj < 4; ++jj)
#pragma unroll
            for (int ks = 0; ks < 2; ++ks) {
                f16x8 kf = *(const f16x8*)&Ks[(jj * 16 + ln15) * 72 + ks * 32 + quad * 8];
                st[jj] = __builtin_amdgcn_mfma_f32_16x16x32_f16(kf, qf[ks], st[jj], 0, 0, 0);
            }

        // ---- online softmax (per lane: 16 scores of query ln15) ----
        float p[4][4];
        float mloc = -3e38f;
#pragma unroll
        for (int jj = 0; jj < 4; ++jj) {
            f32x4 bfr = *(const f32x4*)&biasS[jj * 16 + quad * 4];
#pragma unroll
            for (int r = 0; r < 4; ++r) {
                float sv = st[jj][r] * 0.125f + bfr[r];
                p[jj][r] = sv;
                mloc = fmaxf(mloc, sv);
            }
        }
        mloc = fmaxf(mloc, __shfl_xor(mloc, 16, 64));
        mloc = fmaxf(mloc, __shfl_xor(mloc, 32, 64));
        float mnew = fmaxf(m_i, mloc);
        float alpha = __expf(m_i - mnew);
        m_i = mnew;
        float sloc = 0.f;
#pragma unroll
        for (int jj = 0; jj < 4; ++jj)
#pragma unroll
            for (int r = 0; r < 4; ++r) {
                p[jj][r] = __expf(p[jj][r] - mnew);
                sloc += p[jj][r];
            }
        sloc += __shfl_xor(sloc, 16, 64);
        sloc += __shfl_xor(sloc, 32, 64);
        l_i = l_i * alpha + sloc;

        // rescale O (rows q~ = quad*4+r need alpha of that query)
        float ar[4];
#pragma unroll
        for (int r = 0; r < 4; ++r) ar[r] = __shfl(alpha, quad * 4 + r, 64);
#pragma unroll
        for (int dj = 0; dj < 4; ++dj)
#pragma unroll
            for (int r = 0; r < 4; ++r) oacc[dj][r] *= ar[r];

        // ---- P (C-layout) -> A-operand layout via wave-private LDS ----
        _Float16* pw = &Pw[wave][0];
#pragma unroll
        for (int jj = 0; jj < 4; ++jj)
#pragma unroll
            for (int r = 0; r < 4; ++r)
                pw[ln15 * 72 + jj * 16 + quad * 4 + r] = (_Float16)p[jj][r];
        f16x8 pf[2];
#pragma unroll
        for (int ks = 0; ks < 2; ++ks)
            pf[ks] = *(const f16x8*)&pw[ln15 * 72 + ks * 32 + quad * 8];

        // ---- O += P·V ----
#pragma unroll
        for (int dj = 0; dj < 4; ++dj)
#pragma unroll
            for (int ks = 0; ks < 2; ++ks) {
                f16x8 vf = *(const f16x8*)&VTs[(dj * 16 + ln15) * 72 + ks * 32 + quad * 8];
                oacc[dj] = __builtin_amdgcn_mfma_f32_16x16x32_f16(pf[ks], vf, oacc[dj], 0, 0, 0);
            }
        __syncthreads();
    }

    // ---- epilogue ----
    float linv[4];
#pragma unroll
    for (int r = 0; r < 4; ++r) linv[r] = 1.f / __shfl(l_i, quad * 4 + r, 64);
#pragma unroll
    for (int dj = 0; dj < 4; ++dj)
#pragma unroll
        for (int r = 0; r < 4; ++r) {
            int row = q0 + wave * 16 + quad * 4 + r;
            if (row < SEQ)
                ctx[(size_t)(b * SEQ + row) * 512 + h * 64 + dj * 16 + ln15] =
                    (_Float16)(oacc[dj][r] * linv[r]);
        }
}

// ---------------------------------------------------------------------------
// x = LN(x + r) * g + beta
// ---------------------------------------------------------------------------
__global__ __launch_bounds__(64) void ln_residual_kernel(
    float* __restrict__ x, const float* __restrict__ r,
    const float* __restrict__ g, const float* __restrict__ bta)
{
    const int row = blockIdx.x;
    const int t = threadIdx.x;
    float4* xr = (float4*)(x + (size_t)row * 512);
    const float4* rr = (const float4*)(r + (size_t)row * 512);
    float4 a0 = xr[t], a1 = xr[t + 64];
    float4 b0 = rr[t], b1 = rr[t + 64];
    a0.x += b0.x; a0.y += b0.y; a0.z += b0.z; a0.w += b0.w;
    a1.x += b1.x; a1.y += b1.y; a1.z += b1.z; a1.w += b1.w;
    float s = a0.x + a0.y + a0.z + a0.w + a1.x + a1.y + a1.z + a1.w;
#pragma unroll
    for (int o = 32; o; o >>= 1) s += __shfl_xor(s, o, 64);
    const float mean = s * (1.f / 512.f);
    float sq = 0.f;
    sq += (a0.x - mean) * (a0.x - mean); sq += (a0.y - mean) * (a0.y - mean);
    sq += (a0.z - mean) * (a0.z - mean); sq += (a0.w - mean) * (a0.w - mean);
    sq += (a1.x - mean) * (a1.x - mean); sq += (a1.y - mean) * (a1.y - mean);
    sq += (a1.z - mean) * (a1.z - mean); sq += (a1.w - mean) * (a1.w - mean);
#pragma unroll
    for (int o = 32; o; o >>= 1) sq += __shfl_xor(sq, o, 64);
    const float rstd = rsqrtf(sq * (1.f / 512.f) + 1e-6f);
    const float4 g0 = ((const float4*)g)[t], g1 = ((const float4*)g)[t + 64];
    const float4 e0 = ((const float4*)bta)[t], e1 = ((const float4*)bta)[t + 64];
    float4 o0, o1;
    o0.x = (a0.x - mean) * rstd * g0.x + e0.x;
    o0.y = (a0.y - mean) * rstd * g0.y + e0.y;
    o0.z = (a0.z - mean) * rstd * g0.z + e0.z;
    o0.w = (a0.w - mean) * rstd * g0.w + e0.w;
    o1.x = (a1.x - mean) * rstd * g1.x + e1.x;
    o1.y = (a1.y - mean) * rstd * g1.y + e1.y;
    o1.z = (a1.z - mean) * rstd * g1.z + e1.z;
    o1.w = (a1.w - mean) * rstd * g1.w + e1.w;
    xr[t] = o0; xr[t + 64] = o1;
}

// ---------------------------------------------------------------------------
// Head
// ---------------------------------------------------------------------------
__global__ __launch_bounds__(64) void head1_kernel(
    const float* __restrict__ x, const float* __restrict__ w,
    float* __restrict__ hmlp)
{
    const int n = blockIdx.x & 1023;
    const int b = blockIdx.x >> 10;
    const int t = threadIdx.x;
    const float4* cls = (const float4*)(x + (size_t)b * SEQ * 512);
    const float4* wr = (const float4*)(w + (size_t)n * 512);
    float s = 0.f;
#pragma unroll
    for (int i = 0; i < 2; ++i) {
        float4 a = cls[t + i * 64], c = wr[t + i * 64];
        s += a.x * c.x + a.y * c.y + a.z * c.z + a.w * c.w;
    }
#pragma unroll
    for (int o = 32; o; o >>= 1) s += __shfl_xor(s, o, 64);
    if (t == 0) hmlp[b * 1024 + n] = gelu_f(s);
}

__global__ __launch_bounds__(256) void head2_kernel(
    const float* __restrict__ hmlp, const float* __restrict__ w,
    float* __restrict__ out)
{
    __shared__ float red[4];
    const int b = blockIdx.x;
    const int t = threadIdx.x;
    float s = 0.f;
    for (int i = t; i < 1024; i += 256) s += hmlp[b * 1024 + i] * w[i];
#pragma unroll
    for (int o = 32; o; o >>= 1) s += __shfl_xor(s, o, 64);
    if ((t & 63) == 0) red[t >> 6] = s;
    __syncthreads();
    if (t == 0) out[b] = red[0] + red[1] + red[2] + red[3];
}

// ---------------------------------------------------------------------------
static inline void cast16(const float* s, _Float16* d, long n, hipStream_t st) {
    long n4 = n / 4;
    hipLaunchKernelGGL(cast16_kernel, dim3((n4 + 255) / 256), 256, 0, st, s, d, (int)n4);
}

extern "C" void kernel_launch(void* const* d_in, const int* in_sizes, int n_in,
                              void* d_out, int out_size, void* d_ws, size_t ws_size,
                              hipStream_t stream)
{
    const float* feat_org = (const float*)d_in[0];
    const float* feat_r1  = (const float*)d_in[1];
    const float* feat_r2  = (const float*)d_in[2];
    const float* conv_w   = (const float*)d_in[3];
    const float* conv_b   = (const float*)d_in[4];
    const float* emb_org  = (const float*)d_in[5];
    const float* emb_r1   = (const float*)d_in[6];
    const float* emb_r2   = (const float*)d_in[7];
    const float* pos_emb  = (const float*)d_in[8];
    const float* cls_tok  = (const float*)d_in[9];
    const float* Wq = (const float*)d_in[10];
    const float* bq = (const float*)d_in[11];
    const float* Wk = (const float*)d_in[12];
    const float* bk = (const float*)d_in[13];
    const float* Wv = (const float*)d_in[14];
    const float* bv = (const float*)d_in[15];
    const float* Wo = (const float*)d_in[16];
    const float* bo = (const float*)d_in[17];
    const float* ln1g = (const float*)d_in[18];
    const float* ln1b = (const float*)d_in[19];
    const float* w1 = (const float*)d_in[20];
    const float* b1 = (const float*)d_in[21];
    const float* w2 = (const float*)d_in[22];
    const float* b2 = (const float*)d_in[23];
    const float* ln2g = (const float*)d_in[24];
    const float* ln2b = (const float*)d_in[25];
    const float* pw1 = (const float*)d_in[26];
    const float* pw2 = (const float*)d_in[27];
    const int*   mask = (const int*)d_in[28];

    // -------- workspace layout (bytes) --------
    char* base = (char*)d_ws;
    _Float16* ffh16  = (_Float16*)base;                 // 7296*2048 f16 (also patch16)
    _Float16* patch16 = ffh16;
    base += (size_t)7296 * 2048 * 2;
    float* x   = (float*)base; base += (size_t)7296 * 512 * 4;
    float* att = (float*)base; base += (size_t)7296 * 512 * 4;
    float* tok = att;
    _Float16* qkv16 = (_Float16*)base; base += (size_t)7296 * 1536 * 2;
    _Float16* x16   = (_Float16*)base; base += (size_t)7296 * 512 * 2;
    _Float16* ctx16 = (_Float16*)base; base += (size_t)7296 * 512 * 2;
    _Float16* vT16  = (_Float16*)base; base += (size_t)8 * 8 * 64 * 960 * 2;
    _Float16* wqkv16 = (_Float16*)base; base += (size_t)1536 * 512 * 2;
    _Float16* wo16   = (_Float16*)base; base += (size_t)512 * 512 * 2;
    _Float16* w1_16  = (_Float16*)base; base += (size_t)2048 * 512 * 2;
    _Float16* w2_16  = (_Float16*)base; base += (size_t)512 * 2048 * 2;
    _Float16* convw16 = (_Float16*)base; base += (size_t)512 * 2048 * 2;
    float* bqkv = (float*)base; base += 1536 * 4;
    float* hmlp = (float*)base; base += 8 * 1024 * 4;

    dim3 tb(32, 8);
    hipLaunchKernelGGL(transpose_feat_kernel, dim3(24, 64, 8), tb, 0, stream,
                       feat_org, patch16, 768, 0);
    hipLaunchKernelGGL(transpose_feat_kernel, dim3(4, 64, 8), tb, 0, stream,
                       feat_r1, patch16, 108, 768);
    hipLaunchKernelGGL(transpose_feat_kernel, dim3(2, 64, 8), tb, 0, stream,
                       feat_r2, patch16, 35, 876);
    cast16(conv_w, convw16, (long)512 * 2048, stream);

    hipLaunchKernelGGL((gemm16<0, 0>), dim3(4, 57), 256, 0, stream,
                       patch16, convw16, conv_b, (void*)tok, 7288, 512, 2048);
    hipLaunchKernelGGL(build_x_kernel, dim3(7296), 128, 0, stream,
                       tok, cls_tok, emb_org, emb_r1, emb_r2, pos_emb, x);

    for (int l = 0; l < NLAYER; ++l) {
        const size_t lw = (size_t)l * 512 * 512;
        cast16(Wq + lw, wqkv16, 512 * 512, stream);
        cast16(Wk + lw, wqkv16 + 512 * 512, 512 * 512, stream);
        cast16(Wv + lw, wqkv16 + 1024 * 512, 512 * 512, stream);
        hipMemcpyAsync(bqkv,        bq + l * 512, 512 * 4, hipMemcpyDeviceToDevice, stream);
        hipMemcpyAsync(bqkv + 512,  bk + l * 512, 512 * 4, hipMemcpyDeviceToDevice, stream);
        hipMemcpyAsync(bqkv + 1024, bv + l * 512, 512 * 4, hipMemcpyDeviceToDevice, stream);

        cast16(x, x16, (long)7296 * 512, stream);
        hipLaunchKernelGGL((gemm16<0, 1>), dim3(12, 57), 256, 0, stream,
                           x16, wqkv16, bqkv, (void*)qkv16, 7296, 1536, 512);
        hipLaunchKernelGGL(vtrans_kernel, dim3(15, 8, 8), 256, 0, stream,
                           qkv16, vT16);
        hipLaunchKernelGGL(attn_mfma, dim3(15, 8, 8), 256, 0, stream,
                           qkv16, vT16, mask, ctx16);
        cast16(Wo + lw, wo16, 512 * 512, stream);
        hipLaunchKernelGGL((gemm16<0, 0>), dim3(4, 57), 256, 0, stream,
                           ctx16, wo16, bo + l * 512, (void*)att, 7296, 512, 512);
        hipLaunchKernelGGL(ln_residual_kernel, dim3(7296), 64, 0, stream,
                           x, att, ln1g + l * 512, ln1b + l * 512);

        cast16(w1 + (size_t)l * 2048 * 512, w1_16, (long)2048 * 512, stream);
        cast16(x, x16, (long)7296 * 512, stream);
        hipLaunchKernelGGL((gemm16<1, 1>), dim3(16, 57), 256, 0, stream,
                           x16, w1_16, b1 + l * 2048, (void*)ffh16, 7296, 2048, 512);
        cast16(w2 + (size_t)l * 512 * 2048, w2_16, (long)512 * 2048, stream);
        hipLaunchKernelGGL((gemm16<0, 0>), dim3(4, 57), 256, 0, stream,
                           ffh16, w2_16, b2 + l * 512, (void*)att, 7296, 512, 2048);
        hipLaunchKernelGGL(ln_residual_kernel, dim3(7296), 64, 0, stream,
                           x, att, ln2g + l * 512, ln2b + l * 512);
    }

    hipLaunchKernelGGL(head1_kernel, dim3(8 * 1024), 64, 0, stream, x, pw1, hmlp);
    hipLaunchKernelGGL(head2_kernel, dim3(8), 256, 0, stream, hmlp, pw2, (float*)d_out);
}

// Round 6
// 1741.505 us; speedup vs baseline: 7.8587x; 1.2352x over previous
//
#include <hip/hip_runtime.h>
#include <hip/hip_bf16.h>
#include <math.h>

#define SEQ 912
#define NTOK 911
#define CIN_ 2048
#define NLAYER 6

typedef _Float16 f16x8 __attribute__((ext_vector_type(8)));
typedef _Float16 f16x4 __attribute__((ext_vector_type(4)));
typedef float f32x4 __attribute__((ext_vector_type(4)));

__device__ __forceinline__ float gelu_f(float x) {
    return 0.5f * x * (1.0f + erff(x * 0.70710678118654752f));
}

// ---------------------------------------------------------------------------
// fp16 MFMA NT GEMM, 128x128 tile. QKV=1: N=1536 fused QKV; Q/K sections
// (cols < 1024) go to Cout with ld=ldc; V-section blocks (n0+c0 >= 1024)
// scatter bias-added fp16 directly into vT layout [(b*8+h)*64+d][960].
// ---------------------------------------------------------------------------
template <int ACT, int QKV>
__global__ __launch_bounds__(256) void gemm16(
    const _Float16* __restrict__ A, const _Float16* __restrict__ B,
    const float* __restrict__ bias, _Float16* __restrict__ Cout,
    _Float16* __restrict__ vT, int M, int N, int K, int ldc)
{
    constexpr int BK = 32;
    __shared__ __align__(16) _Float16 As[128 * 40];
    __shared__ __align__(16) _Float16 Bs[128 * 40];
    const int t = threadIdx.x;
    const int m0 = blockIdx.y * 128, n0 = blockIdx.x * 128;
    const int lane = t & 63, w = t >> 6;
    const int r0 = (w >> 1) * 64, c0 = (w & 1) * 64;
    const int ln15 = lane & 15, quad = lane >> 4;
    const int srow = t >> 2, schunk = (t & 3) * 8;

    f32x4 zero = {0.f, 0.f, 0.f, 0.f};
    f32x4 acc[4][4];
#pragma unroll
    for (int i = 0; i < 4; ++i)
#pragma unroll
        for (int j = 0; j < 4; ++j) acc[i][j] = zero;

    for (int k0 = 0; k0 < K; k0 += BK) {
#pragma unroll
        for (int p = 0; p < 2; ++p) {
            int m = p * 64 + srow;
            int gm = m0 + m;
            float4 av = make_float4(0.f, 0.f, 0.f, 0.f);
            if (gm < M) av = *(const float4*)(A + (size_t)gm * K + k0 + schunk);
            *(float4*)&As[m * 40 + schunk] = av;
            int gn = n0 + m;
            float4 bv = make_float4(0.f, 0.f, 0.f, 0.f);
            if (gn < N) bv = *(const float4*)(B + (size_t)gn * K + k0 + schunk);
            *(float4*)&Bs[m * 40 + schunk] = bv;
        }
        __syncthreads();
        f16x8 a[4], b[4];
#pragma unroll
        for (int i = 0; i < 4; ++i)
            a[i] = *(const f16x8*)&As[(r0 + i * 16 + ln15) * 40 + quad * 8];
#pragma unroll
        for (int j = 0; j < 4; ++j)
            b[j] = *(const f16x8*)&Bs[(c0 + j * 16 + ln15) * 40 + quad * 8];
#pragma unroll
        for (int i = 0; i < 4; ++i)
#pragma unroll
            for (int j = 0; j < 4; ++j)
                acc[i][j] = __builtin_amdgcn_mfma_f32_16x16x32_f16(a[i], b[j], acc[i][j], 0, 0, 0);
        __syncthreads();
    }

    const bool isV = QKV && (n0 + c0) >= 1024;
#pragma unroll
    for (int j = 0; j < 4; ++j) {
        int gn = n0 + c0 + j * 16 + ln15;
        float bv = bias[gn];
        if (isV) {
            int chan = gn - 1024;
            int hh = chan >> 6, d = chan & 63;
#pragma unroll
            for (int i = 0; i < 4; ++i) {
                int gmBase = m0 + r0 + i * 16 + quad * 4;   // multiple of 4; 912%4==0
                int bb = gmBase / 912, s = gmBase - bb * 912;
                f16x4 hv4;
#pragma unroll
                for (int r = 0; r < 4; ++r) hv4[r] = (_Float16)(acc[i][j][r] + bv);
                *(f16x4*)&vT[((size_t)((bb * 8 + hh) * 64 + d)) * 960 + s] = hv4;
            }
        } else {
#pragma unroll
            for (int i = 0; i < 4; ++i) {
                int gmBase = m0 + r0 + i * 16 + quad * 4;
#pragma unroll
                for (int r = 0; r < 4; ++r) {
                    int gm = gmBase + r;
                    if (gm >= M) continue;
                    float val = acc[i][j][r] + bv;
                    if (ACT == 1) val = gelu_f(val);
                    Cout[(size_t)gm * ldc + gn] = (_Float16)val;
                }
            }
        }
    }
}

// ---------------------------------------------------------------------------
// Split-K fp16 MFMA NT GEMM, 128x64 tile, 2 k-slices. fp32 partials, no bias.
// ---------------------------------------------------------------------------
__global__ __launch_bounds__(256) void gemm16_splitk(
    const _Float16* __restrict__ A, const _Float16* __restrict__ B,
    float* __restrict__ part, int M, int N, int K)
{
    constexpr int BK = 32;
    __shared__ __align__(16) _Float16 As[128 * 40];
    __shared__ __align__(16) _Float16 Bs[64 * 40];
    const int t = threadIdx.x;
    const int m0 = blockIdx.y * 128, n0 = blockIdx.x * 64;
    const int z = blockIdx.z;
    const int lane = t & 63, w = t >> 6;
    const int r0 = (w >> 1) * 64, c0 = (w & 1) * 32;
    const int ln15 = lane & 15, quad = lane >> 4;
    const int srow = t >> 2, schunk = (t & 3) * 8;
    const int Ks = K >> 1;
    const int kBeg = z * Ks, kEnd = kBeg + Ks;

    f32x4 zero = {0.f, 0.f, 0.f, 0.f};
    f32x4 acc[4][2];
#pragma unroll
    for (int i = 0; i < 4; ++i)
#pragma unroll
        for (int j = 0; j < 2; ++j) acc[i][j] = zero;

    for (int k0 = kBeg; k0 < kEnd; k0 += BK) {
#pragma unroll
        for (int p = 0; p < 2; ++p) {
            int m = p * 64 + srow;
            int gm = m0 + m;
            float4 av = make_float4(0.f, 0.f, 0.f, 0.f);
            if (gm < M) av = *(const float4*)(A + (size_t)gm * K + k0 + schunk);
            *(float4*)&As[m * 40 + schunk] = av;
        }
        {
            int gn = n0 + srow;
            float4 bv = make_float4(0.f, 0.f, 0.f, 0.f);
            if (gn < N) bv = *(const float4*)(B + (size_t)gn * K + k0 + schunk);
            *(float4*)&Bs[srow * 40 + schunk] = bv;
        }
        __syncthreads();
        f16x8 a[4], b[2];
#pragma unroll
        for (int i = 0; i < 4; ++i)
            a[i] = *(const f16x8*)&As[(r0 + i * 16 + ln15) * 40 + quad * 8];
#pragma unroll
        for (int j = 0; j < 2; ++j)
            b[j] = *(const f16x8*)&Bs[(c0 + j * 16 + ln15) * 40 + quad * 8];
#pragma unroll
        for (int i = 0; i < 4; ++i)
#pragma unroll
            for (int j = 0; j < 2; ++j)
                acc[i][j] = __builtin_amdgcn_mfma_f32_16x16x32_f16(a[i], b[j], acc[i][j], 0, 0, 0);
        __syncthreads();
    }

    float* out = part + (size_t)z * M * N;
#pragma unroll
    for (int j = 0; j < 2; ++j) {
        int gn = n0 + c0 + j * 16 + ln15;
#pragma unroll
        for (int i = 0; i < 4; ++i) {
            int gmBase = m0 + r0 + i * 16 + quad * 4;
#pragma unroll
            for (int r = 0; r < 4; ++r) {
                int gm = gmBase + r;
                if (gm < M) out[(size_t)gm * N + gn] = acc[i][j][r];
            }
        }
    }
}

// ---------------------------------------------------------------------------
// prep: casts / packs
// ---------------------------------------------------------------------------
__global__ __launch_bounds__(256) void cast16_kernel(
    const float* __restrict__ src, _Float16* __restrict__ dst, int n4)
{
    int i = blockIdx.x * 256 + threadIdx.x;
    if (i < n4) {
        float4 v = ((const float4*)src)[i];
        f16x4 h;
        h[0] = (_Float16)v.x; h[1] = (_Float16)v.y;
        h[2] = (_Float16)v.z; h[3] = (_Float16)v.w;
        ((f16x4*)dst)[i] = h;
    }
}

__global__ __launch_bounds__(256) void pack_qkvw_kernel(
    const float* __restrict__ Wq, const float* __restrict__ Wk,
    const float* __restrict__ Wv, _Float16* __restrict__ dst)
{
    int idx = blockIdx.x * 256 + threadIdx.x;   // one float4
    if (idx >= 6 * 1536 * 128) return;
    int c4 = idx & 127;
    int rc = idx >> 7;
    int r = rc % 1536;
    int l = rc / 1536;
    const float* src = (r < 512) ? Wq : (r < 1024) ? Wk : Wv;
    float4 v = *(const float4*)(src + ((size_t)l * 512 + (r & 511)) * 512 + c4 * 4);
    f16x4 h;
    h[0] = (_Float16)v.x; h[1] = (_Float16)v.y;
    h[2] = (_Float16)v.z; h[3] = (_Float16)v.w;
    *(f16x4*)(dst + ((size_t)l * 1536 + r) * 512 + c4 * 4) = h;
}

__global__ __launch_bounds__(256) void pack_qkvb_kernel(
    const float* __restrict__ bq, const float* __restrict__ bk,
    const float* __restrict__ bv, float* __restrict__ dst)
{
    int idx = blockIdx.x * 256 + threadIdx.x;
    if (idx < 6 * 1536) {
        int r = idx % 1536, l = idx / 1536;
        const float* s = (r < 512) ? bq : (r < 1024) ? bk : bv;
        dst[idx] = s[l * 512 + (r & 511)];
    }
}

// ---------------------------------------------------------------------------
// Transpose feat (B,CIN,H,W) -> fp16 patch rows
// ---------------------------------------------------------------------------
__global__ __launch_bounds__(256) void transpose_feat_kernel(
    const float* __restrict__ feat, _Float16* __restrict__ patch, int HW, int tok_off)
{
    __shared__ float tile[32][33];
    const int b = blockIdx.z;
    const int c0 = blockIdx.y * 32;
    const int p0 = blockIdx.x * 32;
    const int tx = threadIdx.x, ty = threadIdx.y;
#pragma unroll
    for (int i = 0; i < 4; ++i) {
        int c = c0 + ty + i * 8;
        int p = p0 + tx;
        tile[ty + i * 8][tx] = (p < HW) ? feat[((size_t)b * CIN_ + c) * HW + p] : 0.f;
    }
    __syncthreads();
#pragma unroll
    for (int i = 0; i < 4; ++i) {
        int p = p0 + ty + i * 8;
        int c = c0 + tx;
        if (p < HW)
            patch[((size_t)(b * NTOK + tok_off + p)) * CIN_ + c] = (_Float16)tile[tx][ty + i * 8];
    }
}

// ---------------------------------------------------------------------------
// build x from embed split-K partials: x = part0+part1+conv_b + emb + pos
// ---------------------------------------------------------------------------
__global__ __launch_bounds__(128) void build_x_red(
    const float* __restrict__ part, const float* __restrict__ conv_b,
    const float* __restrict__ cls_token,
    const float* __restrict__ emb_org, const float* __restrict__ emb_r1,
    const float* __restrict__ emb_r2, const float* __restrict__ pos_emb,
    float* __restrict__ x, _Float16* __restrict__ x16)
{
    const size_t ESTR = (size_t)7288 * 512;
    const int row = blockIdx.x;
    const int b = row / SEQ;
    const int tt = row - b * SEQ;
    const int d4 = threadIdx.x;
    float4 o;
    if (tt == 0) {
        o = ((const float4*)cls_token)[d4];
    } else {
        int tp = tt - 1;
        const float* ce; int hh, ww, p;
        if (tp < 768)      { p = tp;       hh = 24; ww = 32; ce = emb_org; }
        else if (tp < 876) { p = tp - 768; hh = 9;  ww = 12; ce = emb_r1; }
        else               { p = tp - 876; hh = 5;  ww = 7;  ce = emb_r2; }
        int i = p / ww, j = p - i * ww;
        int ti = (i * 10) / hh, tj = (j * 10) / ww;
        size_t prow = (size_t)(b * NTOK + tp) * 512;
        float4 t0 = ((const float4*)(part + prow))[d4];
        float4 t1 = ((const float4*)(part + ESTR + prow))[d4];
        float4 cb = ((const float4*)conv_b)[d4];
        float4 cv = ((const float4*)ce)[d4];
        float4 pv = ((const float4*)(pos_emb + (size_t)(ti * 10 + tj) * 512))[d4];
        o.x = t0.x + t1.x + cb.x + cv.x + pv.x;
        o.y = t0.y + t1.y + cb.y + cv.y + pv.y;
        o.z = t0.z + t1.z + cb.z + cv.z + pv.z;
        o.w = t0.w + t1.w + cb.w + cv.w + pv.w;
    }
    ((float4*)(x + (size_t)row * 512))[d4] = o;
    f16x4 h;
    h[0] = (_Float16)o.x; h[1] = (_Float16)o.y;
    h[2] = (_Float16)o.z; h[3] = (_Float16)o.w;
    ((f16x4*)(x16 + (size_t)row * 512))[d4] = h;
}

// ---------------------------------------------------------------------------
// x = LN(x + part0 + part1 + bias) * g + beta; writes fp32 x and fp16 x16
// ---------------------------------------------------------------------------
__global__ __launch_bounds__(64) void ln_residual_red(
    float* __restrict__ x, _Float16* __restrict__ x16,
    const float* __restrict__ part, const float* __restrict__ bias,
    const float* __restrict__ g, const float* __restrict__ bta)
{
    const size_t LSTR = (size_t)7296 * 512;
    const int row = blockIdx.x;
    const int t = threadIdx.x;
    float4* xr = (float4*)(x + (size_t)row * 512);
    const float4* p0 = (const float4*)(part + (size_t)row * 512);
    const float4* p1 = (const float4*)(part + LSTR + (size_t)row * 512);
    const float4* bb = (const float4*)bias;
    float4 a0 = xr[t], a1 = xr[t + 64];
    float4 q0 = p0[t], q1 = p0[t + 64];
    float4 r0 = p1[t], r1 = p1[t + 64];
    float4 c0 = bb[t], c1 = bb[t + 64];
    a0.x += q0.x + r0.x + c0.x; a0.y += q0.y + r0.y + c0.y;
    a0.z += q0.z + r0.z + c0.z; a0.w += q0.w + r0.w + c0.w;
    a1.x += q1.x + r1.x + c1.x; a1.y += q1.y + r1.y + c1.y;
    a1.z += q1.z + r1.z + c1.z; a1.w += q1.w + r1.w + c1.w;
    float s = a0.x + a0.y + a0.z + a0.w + a1.x + a1.y + a1.z + a1.w;
#pragma unroll
    for (int o = 32; o; o >>= 1) s += __shfl_xor(s, o, 64);
    const float mean = s * (1.f / 512.f);
    float sq = 0.f;
    sq += (a0.x - mean) * (a0.x - mean); sq += (a0.y - mean) * (a0.y - mean);
    sq += (a0.z - mean) * (a0.z - mean); sq += (a0.w - mean) * (a0.w - mean);
    sq += (a1.x - mean) * (a1.x - mean); sq += (a1.y - mean) * (a1.y - mean);
    sq += (a1.z - mean) * (a1.z - mean); sq += (a1.w - mean) * (a1.w - mean);
#pragma unroll
    for (int o = 32; o; o >>= 1) sq += __shfl_xor(sq, o, 64);
    const float rstd = rsqrtf(sq * (1.f / 512.f) + 1e-6f);
    const float4 g0 = ((const float4*)g)[t], g1 = ((const float4*)g)[t + 64];
    const float4 e0 = ((const float4*)bta)[t], e1 = ((const float4*)bta)[t + 64];
    float4 o0, o1;
    o0.x = (a0.x - mean) * rstd * g0.x + e0.x;
    o0.y = (a0.y - mean) * rstd * g0.y + e0.y;
    o0.z = (a0.z - mean) * rstd * g0.z + e0.z;
    o0.w = (a0.w - mean) * rstd * g0.w + e0.w;
    o1.x = (a1.x - mean) * rstd * g1.x + e1.x;
    o1.y = (a1.y - mean) * rstd * g1.y + e1.y;
    o1.z = (a1.z - mean) * rstd * g1.z + e1.z;
    o1.w = (a1.w - mean) * rstd * g1.w + e1.w;
    xr[t] = o0; xr[t + 64] = o1;
    f16x4 h0, h1;
    h0[0] = (_Float16)o0.x; h0[1] = (_Float16)o0.y;
    h0[2] = (_Float16)o0.z; h0[3] = (_Float16)o0.w;
    h1[0] = (_Float16)o1.x; h1[1] = (_Float16)o1.y;
    h1[2] = (_Float16)o1.z; h1[3] = (_Float16)o1.w;
    f16x4* xh = (f16x4*)(x16 + (size_t)row * 512);
    xh[t] = h0; xh[t + 64] = h1;
}

// ---------------------------------------------------------------------------
// MFMA flash attention. qk: (B*SEQ, 1024) fp16 [Q | K]; vT from gemm scatter.
// ---------------------------------------------------------------------------
__global__ __launch_bounds__(256) void attn_mfma(
    const _Float16* __restrict__ qk, const _Float16* __restrict__ vT,
    const int* __restrict__ mask, _Float16* __restrict__ ctx)
{
    __shared__ __align__(16) _Float16 Ks[64 * 72];
    __shared__ __align__(16) _Float16 VTs[64 * 72];
    __shared__ __align__(16) _Float16 Pw[4][16 * 72];
    __shared__ float biasS[64];
    const int qt = blockIdx.x, h = blockIdx.y, b = blockIdx.z;
    const int q0 = qt * 64;
    const int t = threadIdx.x;
    const int wave = t >> 6, lane = t & 63;
    const int ln15 = lane & 15, quad = lane >> 4;
    const int qrow = q0 + wave * 16 + ln15;

    f16x8 qf[2];
#pragma unroll
    for (int ks = 0; ks < 2; ++ks) {
        f16x8 z = {0, 0, 0, 0, 0, 0, 0, 0};
        qf[ks] = (qrow < SEQ)
            ? *(const f16x8*)(qk + (size_t)(b * SEQ + qrow) * 1024 + h * 64 + ks * 32 + quad * 8)
            : z;
    }

    f32x4 oacc[4];
    f32x4 zero = {0.f, 0.f, 0.f, 0.f};
#pragma unroll
    for (int dj = 0; dj < 4; ++dj) oacc[dj] = zero;
    float m_i = -1e30f, l_i = 0.f;

    for (int kb = 0; kb < 960; kb += 64) {
#pragma unroll
        for (int i = 0; i < 2; ++i) {
            int u = t + i * 256;
            int r = u >> 3, ch = (u & 7) * 8;
            int kg = kb + r;
            f16x8 kvv = {0, 0, 0, 0, 0, 0, 0, 0};
            if (kg < SEQ) kvv = *(const f16x8*)(qk + (size_t)(b * SEQ + kg) * 1024 + 512 + h * 64 + ch);
            *(f16x8*)&Ks[r * 72 + ch] = kvv;
            f16x8 vv = {0, 0, 0, 0, 0, 0, 0, 0};
            if (kb + ch < SEQ)   // 912 % 8 == 0: chunk fully valid or fully pad
                vv = *(const f16x8*)(vT + ((size_t)((b * 8 + h) * 64 + r)) * 960 + kb + ch);
            *(f16x8*)&VTs[r * 72 + ch] = vv;
        }
        if (t < 64) {
            int kg = kb + t;
            biasS[t] = (kg < SEQ) ? (mask[b * SEQ + kg] ? 0.f : -1e9f) : -2e9f;
        }
        __syncthreads();

        f32x4 st[4];
#pragma unroll
        for (int jj = 0; jj < 4; ++jj) st[jj] = zero;
#pragma unroll
        for (int jj = 0; jj < 4; ++jj)
#pragma unroll
            for (int ks = 0; ks < 2; ++ks) {
                f16x8 kf = *(const f16x8*)&Ks[(jj * 16 + ln15) * 72 + ks * 32 + quad * 8];
                st[jj] = __builtin_amdgcn_mfma_f32_16x16x32_f16(kf, qf[ks], st[jj], 0, 0, 0);
            }

        float p[4][4];
        float mloc = -3e38f;
#pragma unroll
        for (int jj = 0; jj < 4; ++jj) {
            f32x4 bfr = *(const f32x4*)&biasS[jj * 16 + quad * 4];
#pragma unroll
            for (int r = 0; r < 4; ++r) {
                float sv = st[jj][r] * 0.125f + bfr[r];
                p[jj][r] = sv;
                mloc = fmaxf(mloc, sv);
            }
        }
        mloc = fmaxf(mloc, __shfl_xor(mloc, 16, 64));
        mloc = fmaxf(mloc, __shfl_xor(mloc, 32, 64));
        float mnew = fmaxf(m_i, mloc);
        float alpha = __expf(m_i - mnew);
        m_i = mnew;
        float sloc = 0.f;
#pragma unroll
        for (int jj = 0; jj < 4; ++jj)
#pragma unroll
            for (int r = 0; r < 4; ++r) {
                p[jj][r] = __expf(p[jj][r] - mnew);
                sloc += p[jj][r];
            }
        sloc += __shfl_xor(sloc, 16, 64);
        sloc += __shfl_xor(sloc, 32, 64);
        l_i = l_i * alpha + sloc;

        float ar[4];
#pragma unroll
        for (int r = 0; r < 4; ++r) ar[r] = __shfl(alpha, quad * 4 + r, 64);
#pragma unroll
        for (int dj = 0; dj < 4; ++dj)
#pragma unroll
            for (int r = 0; r < 4; ++r) oacc[dj][r] *= ar[r];

        _Float16* pw = &Pw[wave][0];
#pragma unroll
        for (int jj = 0; jj < 4; ++jj)
#pragma unroll
            for (int r = 0; r < 4; ++r)
                pw[ln15 * 72 + jj * 16 + quad * 4 + r] = (_Float16)p[jj][r];
        f16x8 pf[2];
#pragma unroll
        for (int ks = 0; ks < 2; ++ks)
            pf[ks] = *(const f16x8*)&pw[ln15 * 72 + ks * 32 + quad * 8];

#pragma unroll
        for (int dj = 0; dj < 4; ++dj)
#pragma unroll
            for (int ks = 0; ks < 2; ++ks) {
                f16x8 vf = *(const f16x8*)&VTs[(dj * 16 + ln15) * 72 + ks * 32 + quad * 8];
                oacc[dj] = __builtin_amdgcn_mfma_f32_16x16x32_f16(pf[ks], vf, oacc[dj], 0, 0, 0);
            }
        __syncthreads();
    }

    float linv[4];
#pragma unroll
    for (int r = 0; r < 4; ++r) linv[r] = 1.f / __shfl(l_i, quad * 4 + r, 64);
#pragma unroll
    for (int dj = 0; dj < 4; ++dj)
#pragma unroll
        for (int r = 0; r < 4; ++r) {
            int row = q0 + wave * 16 + quad * 4 + r;
            if (row < SEQ)
                ctx[(size_t)(b * SEQ + row) * 512 + h * 64 + dj * 16 + ln15] =
                    (_Float16)(oacc[dj][r] * linv[r]);
        }
}

// ---------------------------------------------------------------------------
// Head
// ---------------------------------------------------------------------------
__global__ __launch_bounds__(64) void head1_kernel(
    const float* __restrict__ x, const float* __restrict__ w,
    float* __restrict__ hmlp)
{
    const int n = blockIdx.x & 1023;
    const int b = blockIdx.x >> 10;
    const int t = threadIdx.x;
    const float4* cls = (const float4*)(x + (size_t)b * SEQ * 512);
    const float4* wr = (const float4*)(w + (size_t)n * 512);
    float s = 0.f;
#pragma unroll
    for (int i = 0; i < 2; ++i) {
        float4 a = cls[t + i * 64], c = wr[t + i * 64];
        s += a.x * c.x + a.y * c.y + a.z * c.z + a.w * c.w;
    }
#pragma unroll
    for (int o = 32; o; o >>= 1) s += __shfl_xor(s, o, 64);
    if (t == 0) hmlp[b * 1024 + n] = gelu_f(s);
}

__global__ __launch_bounds__(256) void head2_kernel(
    const float* __restrict__ hmlp, const float* __restrict__ w,
    float* __restrict__ out)
{
    __shared__ float red[4];
    const int b = blockIdx.x;
    const int t = threadIdx.x;
    float s = 0.f;
    for (int i = t; i < 1024; i += 256) s += hmlp[b * 1024 + i] * w[i];
#pragma unroll
    for (int o = 32; o; o >>= 1) s += __shfl_xor(s, o, 64);
    if ((t & 63) == 0) red[t >> 6] = s;
    __syncthreads();
    if (t == 0) out[b] = red[0] + red[1] + red[2] + red[3];
}

// ---------------------------------------------------------------------------
extern "C" void kernel_launch(void* const* d_in, const int* in_sizes, int n_in,
                              void* d_out, int out_size, void* d_ws, size_t ws_size,
                              hipStream_t stream)
{
    const float* feat_org = (const float*)d_in[0];
    const float* feat_r1  = (const float*)d_in[1];
    const float* feat_r2  = (const float*)d_in[2];
    const float* conv_w   = (const float*)d_in[3];
    const float* conv_b   = (const float*)d_in[4];
    const float* emb_org  = (const float*)d_in[5];
    const float* emb_r1   = (const float*)d_in[6];
    const float* emb_r2   = (const float*)d_in[7];
    const float* pos_emb  = (const float*)d_in[8];
    const float* cls_tok  = (const float*)d_in[9];
    const float* Wq = (const float*)d_in[10];
    const float* bq = (const float*)d_in[11];
    const float* Wk = (const float*)d_in[12];
    const float* bk = (const float*)d_in[13];
    const float* Wv = (const float*)d_in[14];
    const float* bv = (const float*)d_in[15];
    const float* Wo = (const float*)d_in[16];
    const float* bo = (const float*)d_in[17];
    const float* ln1g = (const float*)d_in[18];
    const float* ln1b = (const float*)d_in[19];
    const float* w1 = (const float*)d_in[20];
    const float* b1 = (const float*)d_in[21];
    const float* w2 = (const float*)d_in[22];
    const float* b2 = (const float*)d_in[23];
    const float* ln2g = (const float*)d_in[24];
    const float* ln2b = (const float*)d_in[25];
    const float* pw1 = (const float*)d_in[26];
    const float* pw2 = (const float*)d_in[27];
    const int*   mask = (const int*)d_in[28];

    // -------- workspace layout (total ~94.8 MB; R4's proven 108.2 MB fit) ----
    char* base = (char*)d_ws;
    _Float16* ffh16 = (_Float16*)base;                    // 29,884,416 (patch16 in embed)
    _Float16* patch16 = ffh16;
    base += (size_t)7296 * 2048 * 2;
    float* x = (float*)base; base += (size_t)7296 * 512 * 4;          // 14,942,208
    _Float16* qk16 = (_Float16*)base; base += (size_t)7296 * 1024 * 2; // 14,942,208 (Q|K, ld=1024)
    _Float16* vT16 = (_Float16*)base; base += (size_t)8 * 8 * 64 * 960 * 2; // 7,864,320
    _Float16* ctx16 = (_Float16*)base; base += (size_t)7296 * 512 * 2;      // 7,471,104
    _Float16* x16   = (_Float16*)base; base += (size_t)7296 * 512 * 2;      // 7,471,104
    _Float16* wqkv_all = (_Float16*)base; base += (size_t)6 * 1536 * 512 * 2; // 9,437,184
    _Float16* wo_all   = (_Float16*)base; base += (size_t)6 * 512 * 512 * 2;  // 3,145,728
    _Float16* w1_l16   = (_Float16*)base; base += (size_t)2048 * 512 * 2;     // 2,097,152
    _Float16* w2_l16   = (_Float16*)base; base += (size_t)512 * 2048 * 2;     // 2,097,152
    float* bqkv_all = (float*)base; base += 6 * 1536 * 4;
    float* hmlp = (float*)base; base += 8 * 1024 * 4;

    // fp32 split-K partial overlays (dead regions at time of use):
    //  - O-proj partials: ffh region (2*7296*512*4 = 29,884,416 B, exact fit)
    //  - FFN2 + embed partials: qk16+vT16+ctx16 contiguous (30,277,632 B)
    float* partO = (float*)ffh16;
    float* partF = (float*)qk16;
    // convw16 lives in x16 region during embed (x16 first written after embed gemm)
    _Float16* convw16 = x16;

    // -------- prep --------
    dim3 tb(32, 8);
    hipLaunchKernelGGL(transpose_feat_kernel, dim3(24, 64, 8), tb, 0, stream,
                       feat_org, patch16, 768, 0);
    hipLaunchKernelGGL(transpose_feat_kernel, dim3(4, 64, 8), tb, 0, stream,
                       feat_r1, patch16, 108, 768);
    hipLaunchKernelGGL(transpose_feat_kernel, dim3(2, 64, 8), tb, 0, stream,
                       feat_r2, patch16, 35, 876);
    hipLaunchKernelGGL(cast16_kernel, dim3(1024), 256, 0, stream,
                       conv_w, convw16, 512 * 2048 / 4);
    hipLaunchKernelGGL(cast16_kernel, dim3(1536), 256, 0, stream,
                       Wo, wo_all, 6 * 512 * 512 / 4);
    hipLaunchKernelGGL(pack_qkvw_kernel, dim3(4608), 256, 0, stream,
                       Wq, Wk, Wv, wqkv_all);
    hipLaunchKernelGGL(pack_qkvb_kernel, dim3(36), 256, 0, stream,
                       bq, bk, bv, bqkv_all);

    // -------- embed --------
    hipLaunchKernelGGL(gemm16_splitk, dim3(8, 57, 2), 256, 0, stream,
                       patch16, convw16, partF, 7288, 512, 2048);
    hipLaunchKernelGGL(build_x_red, dim3(7296), 128, 0, stream,
                       partF, conv_b, cls_tok, emb_org, emb_r1, emb_r2, pos_emb, x, x16);

    // -------- layers --------
    for (int l = 0; l < NLAYER; ++l) {
        hipLaunchKernelGGL(cast16_kernel, dim3(1024), 256, 0, stream,
                           w1 + (size_t)l * 2048 * 512, w1_l16, 2048 * 512 / 4);
        hipLaunchKernelGGL(cast16_kernel, dim3(1024), 256, 0, stream,
                           w2 + (size_t)l * 512 * 2048, w2_l16, 512 * 2048 / 4);
        hipLaunchKernelGGL((gemm16<0, 1>), dim3(12, 57), 256, 0, stream,
                           x16, wqkv_all + (size_t)l * 1536 * 512, bqkv_all + l * 1536,
                           qk16, vT16, 7296, 1536, 512, 1024);
        hipLaunchKernelGGL(attn_mfma, dim3(15, 8, 8), 256, 0, stream,
                           qk16, vT16, mask, ctx16);
        hipLaunchKernelGGL(gemm16_splitk, dim3(8, 57, 2), 256, 0, stream,
                           ctx16, wo_all + (size_t)l * 512 * 512, partO, 7296, 512, 512);
        hipLaunchKernelGGL(ln_residual_red, dim3(7296), 64, 0, stream,
                           x, x16, partO, bo + l * 512, ln1g + l * 512, ln1b + l * 512);
        hipLaunchKernelGGL((gemm16<1, 0>), dim3(16, 57), 256, 0, stream,
                           x16, w1_l16, b1 + l * 2048,
                           ffh16, (_Float16*)nullptr, 7296, 2048, 512, 2048);
        hipLaunchKernelGGL(gemm16_splitk, dim3(8, 57, 2), 256, 0, stream,
                           ffh16, w2_l16, partF, 7296, 512, 2048);
        hipLaunchKernelGGL(ln_residual_red, dim3(7296), 64, 0, stream,
                           x, x16, partF, b2 + l * 512, ln2g + l * 512, ln2b + l * 512);
    }

    hipLaunchKernelGGL(head1_kernel, dim3(8 * 1024), 64, 0, stream, x, pw1, hmlp);
    hipLaunchKernelGGL(head2_kernel, dim3(8), 256, 0, stream, hmlp, pw2, (float*)d_out);
}

// Round 7
// 1535.558 us; speedup vs baseline: 8.9127x; 1.1341x over previous
//
#include <hip/hip_runtime.h>
#include <hip/hip_bf16.h>
#include <math.h>

#define SEQ 912
#define NTOK 911
#define CIN_ 2048
#define NLAYER 6

typedef _Float16 f16x8 __attribute__((ext_vector_type(8)));
typedef _Float16 f16x4 __attribute__((ext_vector_type(4)));
typedef float f32x4 __attribute__((ext_vector_type(4)));

__device__ __forceinline__ float gelu_f(float x) {
    return 0.5f * x * (1.0f + erff(x * 0.70710678118654752f));
}

// ---------------------------------------------------------------------------
// fp16 MFMA NT GEMM, 128x128 tile, register-prefetch pipelined K-loop,
// LDS-transposed coalesced epilogue. QKV=1: N=1536 fused QKV; V-blocks
// (n0 >= 1024) scatter bias-added fp16 into vT [(b*8+h)*64+d][960].
// ---------------------------------------------------------------------------
template <int ACT, int QKV>
__global__ __launch_bounds__(256) void gemm16(
    const _Float16* __restrict__ A, const _Float16* __restrict__ B,
    const float* __restrict__ bias, _Float16* __restrict__ Cout,
    _Float16* __restrict__ vT, int M, int N, int K, int ldc)
{
    constexpr int BK = 32;
    __shared__ __align__(16) char smem[20480];
    _Float16* As = (_Float16*)smem;           // 128 x 40 halves
    _Float16* Bs = As + 128 * 40;             // 128 x 40 halves
    _Float16* Cs = (_Float16*)smem;           // epilogue reuse: 64 x 136 halves
    const int t = threadIdx.x;
    const int m0 = blockIdx.y * 128, n0 = blockIdx.x * 128;
    const int lane = t & 63, w = t >> 6;
    const int r0 = (w >> 1) * 64, c0 = (w & 1) * 64;
    const int ln15 = lane & 15, quad = lane >> 4;
    const int srow = t >> 2, schunk = (t & 3) * 8;

    f32x4 zero = {0.f, 0.f, 0.f, 0.f};
    f32x4 acc[4][4];
#pragma unroll
    for (int i = 0; i < 4; ++i)
#pragma unroll
        for (int j = 0; j < 4; ++j) acc[i][j] = zero;

    // prologue: prefetch k0 = 0 into registers
    float4 pa[2], pb[2];
#pragma unroll
    for (int p = 0; p < 2; ++p) {
        int m = p * 64 + srow;
        int gm = m0 + m, gn = n0 + m;
        pa[p] = make_float4(0.f, 0.f, 0.f, 0.f);
        pb[p] = make_float4(0.f, 0.f, 0.f, 0.f);
        if (gm < M) pa[p] = *(const float4*)(A + (size_t)gm * K + schunk);
        if (gn < N) pb[p] = *(const float4*)(B + (size_t)gn * K + schunk);
    }

    for (int k0 = 0; k0 < K; k0 += BK) {
#pragma unroll
        for (int p = 0; p < 2; ++p) {
            int m = p * 64 + srow;
            *(float4*)&As[m * 40 + schunk] = pa[p];
            *(float4*)&Bs[m * 40 + schunk] = pb[p];
        }
        __syncthreads();
        int k1 = k0 + BK;
        if (k1 < K) {
#pragma unroll
            for (int p = 0; p < 2; ++p) {
                int m = p * 64 + srow;
                int gm = m0 + m, gn = n0 + m;
                pa[p] = make_float4(0.f, 0.f, 0.f, 0.f);
                pb[p] = make_float4(0.f, 0.f, 0.f, 0.f);
                if (gm < M) pa[p] = *(const float4*)(A + (size_t)gm * K + k1 + schunk);
                if (gn < N) pb[p] = *(const float4*)(B + (size_t)gn * K + k1 + schunk);
            }
        }
        f16x8 a[4], b[4];
#pragma unroll
        for (int i = 0; i < 4; ++i)
            a[i] = *(const f16x8*)&As[(r0 + i * 16 + ln15) * 40 + quad * 8];
#pragma unroll
        for (int j = 0; j < 4; ++j)
            b[j] = *(const f16x8*)&Bs[(c0 + j * 16 + ln15) * 40 + quad * 8];
#pragma unroll
        for (int i = 0; i < 4; ++i)
#pragma unroll
            for (int j = 0; j < 4; ++j)
                acc[i][j] = __builtin_amdgcn_mfma_f32_16x16x32_f16(a[i], b[j], acc[i][j], 0, 0, 0);
        __syncthreads();
    }

    if (QKV && n0 >= 1024) {
        // V-section: scatter into vT (per-block uniform branch)
#pragma unroll
        for (int j = 0; j < 4; ++j) {
            int gn = n0 + c0 + j * 16 + ln15;
            float bv = bias[gn];
            int chan = gn - 1024;
            int hh = chan >> 6, d = chan & 63;
#pragma unroll
            for (int i = 0; i < 4; ++i) {
                int gmBase = m0 + r0 + i * 16 + quad * 4;   // mult of 4; 912%4==0
                int bb = gmBase / 912, s = gmBase - bb * 912;
                f16x4 hv4;
#pragma unroll
                for (int r = 0; r < 4; ++r) hv4[r] = (_Float16)(acc[i][j][r] + bv);
                *(f16x4*)&vT[((size_t)((bb * 8 + hh) * 64 + d)) * 960 + s] = hv4;
            }
        }
    } else {
        // coalesced epilogue: stage 64-row halves in LDS, stream f16x8 out
#pragma unroll
        for (int half = 0; half < 2; ++half) {
            if ((w >> 1) == half) {
#pragma unroll
                for (int j = 0; j < 4; ++j) {
                    float bv = bias[n0 + c0 + j * 16 + ln15];
#pragma unroll
                    for (int i = 0; i < 4; ++i)
#pragma unroll
                        for (int r = 0; r < 4; ++r) {
                            float val = acc[i][j][r] + bv;
                            if (ACT == 1) val = gelu_f(val);
                            Cs[(i * 16 + quad * 4 + r) * 136 + c0 + j * 16 + ln15] = (_Float16)val;
                        }
                }
            }
            __syncthreads();
#pragma unroll
            for (int uu = 0; uu < 4; ++uu) {
                int u = t + uu * 256;
                int lr = u >> 4, ch = (u & 15) * 8;
                int gm = m0 + half * 64 + lr;
                if (gm < M)
                    *(f16x8*)&Cout[(size_t)gm * ldc + n0 + ch] = *(const f16x8*)&Cs[lr * 136 + ch];
            }
            __syncthreads();
        }
    }
}

// ---------------------------------------------------------------------------
// Split-K fp16 MFMA NT GEMM, 128x64 tile, 2 k-slices, register prefetch.
// fp32 partials (64 B segment stores - acceptable coalescing), no bias.
// ---------------------------------------------------------------------------
__global__ __launch_bounds__(256) void gemm16_splitk(
    const _Float16* __restrict__ A, const _Float16* __restrict__ B,
    float* __restrict__ part, int M, int N, int K)
{
    constexpr int BK = 32;
    __shared__ __align__(16) _Float16 As[128 * 40];
    __shared__ __align__(16) _Float16 Bs[64 * 40];
    const int t = threadIdx.x;
    const int m0 = blockIdx.y * 128, n0 = blockIdx.x * 64;
    const int z = blockIdx.z;
    const int lane = t & 63, w = t >> 6;
    const int r0 = (w >> 1) * 64, c0 = (w & 1) * 32;
    const int ln15 = lane & 15, quad = lane >> 4;
    const int srow = t >> 2, schunk = (t & 3) * 8;
    const int Ks = K >> 1;
    const int kBeg = z * Ks, kEnd = kBeg + Ks;

    f32x4 zero = {0.f, 0.f, 0.f, 0.f};
    f32x4 acc[4][2];
#pragma unroll
    for (int i = 0; i < 4; ++i)
#pragma unroll
        for (int j = 0; j < 2; ++j) acc[i][j] = zero;

    float4 pa[2], pb;
#pragma unroll
    for (int p = 0; p < 2; ++p) {
        int m = p * 64 + srow;
        int gm = m0 + m;
        pa[p] = make_float4(0.f, 0.f, 0.f, 0.f);
        if (gm < M) pa[p] = *(const float4*)(A + (size_t)gm * K + kBeg + schunk);
    }
    {
        int gn = n0 + srow;
        pb = make_float4(0.f, 0.f, 0.f, 0.f);
        if (gn < N) pb = *(const float4*)(B + (size_t)gn * K + kBeg + schunk);
    }

    for (int k0 = kBeg; k0 < kEnd; k0 += BK) {
#pragma unroll
        for (int p = 0; p < 2; ++p) {
            int m = p * 64 + srow;
            *(float4*)&As[m * 40 + schunk] = pa[p];
        }
        *(float4*)&Bs[srow * 40 + schunk] = pb;
        __syncthreads();
        int k1 = k0 + BK;
        if (k1 < kEnd) {
#pragma unroll
            for (int p = 0; p < 2; ++p) {
                int m = p * 64 + srow;
                int gm = m0 + m;
                pa[p] = make_float4(0.f, 0.f, 0.f, 0.f);
                if (gm < M) pa[p] = *(const float4*)(A + (size_t)gm * K + k1 + schunk);
            }
            int gn = n0 + srow;
            pb = make_float4(0.f, 0.f, 0.f, 0.f);
            if (gn < N) pb = *(const float4*)(B + (size_t)gn * K + k1 + schunk);
        }
        f16x8 a[4], b[2];
#pragma unroll
        for (int i = 0; i < 4; ++i)
            a[i] = *(const f16x8*)&As[(r0 + i * 16 + ln15) * 40 + quad * 8];
#pragma unroll
        for (int j = 0; j < 2; ++j)
            b[j] = *(const f16x8*)&Bs[(c0 + j * 16 + ln15) * 40 + quad * 8];
#pragma unroll
        for (int i = 0; i < 4; ++i)
#pragma unroll
            for (int j = 0; j < 2; ++j)
                acc[i][j] = __builtin_amdgcn_mfma_f32_16x16x32_f16(a[i], b[j], acc[i][j], 0, 0, 0);
        __syncthreads();
    }

    float* out = part + (size_t)z * M * N;
#pragma unroll
    for (int j = 0; j < 2; ++j) {
        int gn = n0 + c0 + j * 16 + ln15;
#pragma unroll
        for (int i = 0; i < 4; ++i) {
            int gmBase = m0 + r0 + i * 16 + quad * 4;
#pragma unroll
            for (int r = 0; r < 4; ++r) {
                int gm = gmBase + r;
                if (gm < M) out[(size_t)gm * N + gn] = acc[i][j][r];
            }
        }
    }
}

// ---------------------------------------------------------------------------
// prep: casts / packs
// ---------------------------------------------------------------------------
__global__ __launch_bounds__(256) void cast16_kernel(
    const float* __restrict__ src, _Float16* __restrict__ dst, int n4)
{
    int i = blockIdx.x * 256 + threadIdx.x;
    if (i < n4) {
        float4 v = ((const float4*)src)[i];
        f16x4 h;
        h[0] = (_Float16)v.x; h[1] = (_Float16)v.y;
        h[2] = (_Float16)v.z; h[3] = (_Float16)v.w;
        ((f16x4*)dst)[i] = h;
    }
}

__global__ __launch_bounds__(256) void cast2_kernel(
    const float* __restrict__ s1, _Float16* __restrict__ d1, int n4_1,
    const float* __restrict__ s2, _Float16* __restrict__ d2, int n4_2)
{
    int i = blockIdx.x * 256 + threadIdx.x;
    if (i < n4_1) {
        float4 v = ((const float4*)s1)[i];
        f16x4 h;
        h[0] = (_Float16)v.x; h[1] = (_Float16)v.y;
        h[2] = (_Float16)v.z; h[3] = (_Float16)v.w;
        ((f16x4*)d1)[i] = h;
    } else {
        int j = i - n4_1;
        if (j < n4_2) {
            float4 v = ((const float4*)s2)[j];
            f16x4 h;
            h[0] = (_Float16)v.x; h[1] = (_Float16)v.y;
            h[2] = (_Float16)v.z; h[3] = (_Float16)v.w;
            ((f16x4*)d2)[j] = h;
        }
    }
}

__global__ __launch_bounds__(256) void pack_qkvw_kernel(
    const float* __restrict__ Wq, const float* __restrict__ Wk,
    const float* __restrict__ Wv, _Float16* __restrict__ dst)
{
    int idx = blockIdx.x * 256 + threadIdx.x;   // one float4
    if (idx >= 6 * 1536 * 128) return;
    int c4 = idx & 127;
    int rc = idx >> 7;
    int r = rc % 1536;
    int l = rc / 1536;
    const float* src = (r < 512) ? Wq : (r < 1024) ? Wk : Wv;
    float4 v = *(const float4*)(src + ((size_t)l * 512 + (r & 511)) * 512 + c4 * 4);
    f16x4 h;
    h[0] = (_Float16)v.x; h[1] = (_Float16)v.y;
    h[2] = (_Float16)v.z; h[3] = (_Float16)v.w;
    *(f16x4*)(dst + ((size_t)l * 1536 + r) * 512 + c4 * 4) = h;
}

__global__ __launch_bounds__(256) void pack_qkvb_kernel(
    const float* __restrict__ bq, const float* __restrict__ bk,
    const float* __restrict__ bv, float* __restrict__ dst)
{
    int idx = blockIdx.x * 256 + threadIdx.x;
    if (idx < 6 * 1536) {
        int r = idx % 1536, l = idx / 1536;
        const float* s = (r < 512) ? bq : (r < 1024) ? bk : bv;
        dst[idx] = s[l * 512 + (r & 511)];
    }
}

// ---------------------------------------------------------------------------
// Transpose feat (B,CIN,H,W) -> fp16 patch rows
// ---------------------------------------------------------------------------
__global__ __launch_bounds__(256) void transpose_feat_kernel(
    const float* __restrict__ feat, _Float16* __restrict__ patch, int HW, int tok_off)
{
    __shared__ float tile[32][33];
    const int b = blockIdx.z;
    const int c0 = blockIdx.y * 32;
    const int p0 = blockIdx.x * 32;
    const int tx = threadIdx.x, ty = threadIdx.y;
#pragma unroll
    for (int i = 0; i < 4; ++i) {
        int c = c0 + ty + i * 8;
        int p = p0 + tx;
        tile[ty + i * 8][tx] = (p < HW) ? feat[((size_t)b * CIN_ + c) * HW + p] : 0.f;
    }
    __syncthreads();
#pragma unroll
    for (int i = 0; i < 4; ++i) {
        int p = p0 + ty + i * 8;
        int c = c0 + tx;
        if (p < HW)
            patch[((size_t)(b * NTOK + tok_off + p)) * CIN_ + c] = (_Float16)tile[tx][ty + i * 8];
    }
}

// ---------------------------------------------------------------------------
// build x from embed split-K partials: x = part0+part1+conv_b + emb + pos
// ---------------------------------------------------------------------------
__global__ __launch_bounds__(128) void build_x_red(
    const float* __restrict__ part, const float* __restrict__ conv_b,
    const float* __restrict__ cls_token,
    const float* __restrict__ emb_org, const float* __restrict__ emb_r1,
    const float* __restrict__ emb_r2, const float* __restrict__ pos_emb,
    float* __restrict__ x, _Float16* __restrict__ x16)
{
    const size_t ESTR = (size_t)7288 * 512;
    const int row = blockIdx.x;
    const int b = row / SEQ;
    const int tt = row - b * SEQ;
    const int d4 = threadIdx.x;
    float4 o;
    if (tt == 0) {
        o = ((const float4*)cls_token)[d4];
    } else {
        int tp = tt - 1;
        const float* ce; int hh, ww, p;
        if (tp < 768)      { p = tp;       hh = 24; ww = 32; ce = emb_org; }
        else if (tp < 876) { p = tp - 768; hh = 9;  ww = 12; ce = emb_r1; }
        else               { p = tp - 876; hh = 5;  ww = 7;  ce = emb_r2; }
        int i = p / ww, j = p - i * ww;
        int ti = (i * 10) / hh, tj = (j * 10) / ww;
        size_t prow = (size_t)(b * NTOK + tp) * 512;
        float4 t0 = ((const float4*)(part + prow))[d4];
        float4 t1 = ((const float4*)(part + ESTR + prow))[d4];
        float4 cb = ((const float4*)conv_b)[d4];
        float4 cv = ((const float4*)ce)[d4];
        float4 pv = ((const float4*)(pos_emb + (size_t)(ti * 10 + tj) * 512))[d4];
        o.x = t0.x + t1.x + cb.x + cv.x + pv.x;
        o.y = t0.y + t1.y + cb.y + cv.y + pv.y;
        o.z = t0.z + t1.z + cb.z + cv.z + pv.z;
        o.w = t0.w + t1.w + cb.w + cv.w + pv.w;
    }
    ((float4*)(x + (size_t)row * 512))[d4] = o;
    f16x4 h;
    h[0] = (_Float16)o.x; h[1] = (_Float16)o.y;
    h[2] = (_Float16)o.z; h[3] = (_Float16)o.w;
    ((f16x4*)(x16 + (size_t)row * 512))[d4] = h;
}

// ---------------------------------------------------------------------------
// x = LN(x + part0 + part1 + bias) * g + beta; writes fp32 x and fp16 x16
// ---------------------------------------------------------------------------
__global__ __launch_bounds__(64) void ln_residual_red(
    float* __restrict__ x, _Float16* __restrict__ x16,
    const float* __restrict__ part, const float* __restrict__ bias,
    const float* __restrict__ g, const float* __restrict__ bta)
{
    const size_t LSTR = (size_t)7296 * 512;
    const int row = blockIdx.x;
    const int t = threadIdx.x;
    float4* xr = (float4*)(x + (size_t)row * 512);
    const float4* p0 = (const float4*)(part + (size_t)row * 512);
    const float4* p1 = (const float4*)(part + LSTR + (size_t)row * 512);
    const float4* bb = (const float4*)bias;
    float4 a0 = xr[t], a1 = xr[t + 64];
    float4 q0 = p0[t], q1 = p0[t + 64];
    float4 r0 = p1[t], r1 = p1[t + 64];
    float4 c0 = bb[t], c1 = bb[t + 64];
    a0.x += q0.x + r0.x + c0.x; a0.y += q0.y + r0.y + c0.y;
    a0.z += q0.z + r0.z + c0.z; a0.w += q0.w + r0.w + c0.w;
    a1.x += q1.x + r1.x + c1.x; a1.y += q1.y + r1.y + c1.y;
    a1.z += q1.z + r1.z + c1.z; a1.w += q1.w + r1.w + c1.w;
    float s = a0.x + a0.y + a0.z + a0.w + a1.x + a1.y + a1.z + a1.w;
#pragma unroll
    for (int o = 32; o; o >>= 1) s += __shfl_xor(s, o, 64);
    const float mean = s * (1.f / 512.f);
    float sq = 0.f;
    sq += (a0.x - mean) * (a0.x - mean); sq += (a0.y - mean) * (a0.y - mean);
    sq += (a0.z - mean) * (a0.z - mean); sq += (a0.w - mean) * (a0.w - mean);
    sq += (a1.x - mean) * (a1.x - mean); sq += (a1.y - mean) * (a1.y - mean);
    sq += (a1.z - mean) * (a1.z - mean); sq += (a1.w - mean) * (a1.w - mean);
#pragma unroll
    for (int o = 32; o; o >>= 1) sq += __shfl_xor(sq, o, 64);
    const float rstd = rsqrtf(sq * (1.f / 512.f) + 1e-6f);
    const float4 g0 = ((const float4*)g)[t], g1 = ((const float4*)g)[t + 64];
    const float4 e0 = ((const float4*)bta)[t], e1 = ((const float4*)bta)[t + 64];
    float4 o0, o1;
    o0.x = (a0.x - mean) * rstd * g0.x + e0.x;
    o0.y = (a0.y - mean) * rstd * g0.y + e0.y;
    o0.z = (a0.z - mean) * rstd * g0.z + e0.z;
    o0.w = (a0.w - mean) * rstd * g0.w + e0.w;
    o1.x = (a1.x - mean) * rstd * g1.x + e1.x;
    o1.y = (a1.y - mean) * rstd * g1.y + e1.y;
    o1.z = (a1.z - mean) * rstd * g1.z + e1.z;
    o1.w = (a1.w - mean) * rstd * g1.w + e1.w;
    xr[t] = o0; xr[t + 64] = o1;
    f16x4 h0, h1;
    h0[0] = (_Float16)o0.x; h0[1] = (_Float16)o0.y;
    h0[2] = (_Float16)o0.z; h0[3] = (_Float16)o0.w;
    h1[0] = (_Float16)o1.x; h1[1] = (_Float16)o1.y;
    h1[2] = (_Float16)o1.z; h1[3] = (_Float16)o1.w;
    f16x4* xh = (f16x4*)(x16 + (size_t)row * 512);
    xh[t] = h0; xh[t + 64] = h1;
}

// ---------------------------------------------------------------------------
// MFMA flash attention. qk: (B*SEQ, 1024) fp16 [Q | K]; vT from gemm scatter.
// ---------------------------------------------------------------------------
__global__ __launch_bounds__(256) void attn_mfma(
    const _Float16* __restrict__ qk, const _Float16* __restrict__ vT,
    const int* __restrict__ mask, _Float16* __restrict__ ctx)
{
    __shared__ __align__(16) _Float16 Ks[64 * 72];
    __shared__ __align__(16) _Float16 VTs[64 * 72];
    __shared__ __align__(16) _Float16 Pw[4][16 * 72];
    __shared__ float biasS[64];
    const int qt = blockIdx.x, h = blockIdx.y, b = blockIdx.z;
    const int q0 = qt * 64;
    const int t = threadIdx.x;
    const int wave = t >> 6, lane = t & 63;
    const int ln15 = lane & 15, quad = lane >> 4;
    const int qrow = q0 + wave * 16 + ln15;

    f16x8 qf[2];
#pragma unroll
    for (int ks = 0; ks < 2; ++ks) {
        f16x8 z = {0, 0, 0, 0, 0, 0, 0, 0};
        qf[ks] = (qrow < SEQ)
            ? *(const f16x8*)(qk + (size_t)(b * SEQ + qrow) * 1024 + h * 64 + ks * 32 + quad * 8)
            : z;
    }

    f32x4 oacc[4];
    f32x4 zero = {0.f, 0.f, 0.f, 0.f};
#pragma unroll
    for (int dj = 0; dj < 4; ++dj) oacc[dj] = zero;
    float m_i = -1e30f, l_i = 0.f;

    for (int kb = 0; kb < 960; kb += 64) {
#pragma unroll
        for (int i = 0; i < 2; ++i) {
            int u = t + i * 256;
            int r = u >> 3, ch = (u & 7) * 8;
            int kg = kb + r;
            f16x8 kvv = {0, 0, 0, 0, 0, 0, 0, 0};
            if (kg < SEQ) kvv = *(const f16x8*)(qk + (size_t)(b * SEQ + kg) * 1024 + 512 + h * 64 + ch);
            *(f16x8*)&Ks[r * 72 + ch] = kvv;
            f16x8 vv = {0, 0, 0, 0, 0, 0, 0, 0};
            if (kb + ch < SEQ)   // 912 % 8 == 0: chunk fully valid or fully pad
                vv = *(const f16x8*)(vT + ((size_t)((b * 8 + h) * 64 + r)) * 960 + kb + ch);
            *(f16x8*)&VTs[r * 72 + ch] = vv;
        }
        if (t < 64) {
            int kg = kb + t;
            biasS[t] = (kg < SEQ) ? (mask[b * SEQ + kg] ? 0.f : -1e9f) : -2e9f;
        }
        __syncthreads();

        f32x4 st[4];
#pragma unroll
        for (int jj = 0; jj < 4; ++jj) st[jj] = zero;
#pragma unroll
        for (int jj = 0; jj < 4; ++jj)
#pragma unroll
            for (int ks = 0; ks < 2; ++ks) {
                f16x8 kf = *(const f16x8*)&Ks[(jj * 16 + ln15) * 72 + ks * 32 + quad * 8];
                st[jj] = __builtin_amdgcn_mfma_f32_16x16x32_f16(kf, qf[ks], st[jj], 0, 0, 0);
            }

        float p[4][4];
        float mloc = -3e38f;
#pragma unroll
        for (int jj = 0; jj < 4; ++jj) {
            f32x4 bfr = *(const f32x4*)&biasS[jj * 16 + quad * 4];
#pragma unroll
            for (int r = 0; r < 4; ++r) {
                float sv = st[jj][r] * 0.125f + bfr[r];
                p[jj][r] = sv;
                mloc = fmaxf(mloc, sv);
            }
        }
        mloc = fmaxf(mloc, __shfl_xor(mloc, 16, 64));
        mloc = fmaxf(mloc, __shfl_xor(mloc, 32, 64));
        float mnew = fmaxf(m_i, mloc);
        float alpha = __expf(m_i - mnew);
        m_i = mnew;
        float sloc = 0.f;
#pragma unroll
        for (int jj = 0; jj < 4; ++jj)
#pragma unroll
            for (int r = 0; r < 4; ++r) {
                p[jj][r] = __expf(p[jj][r] - mnew);
                sloc += p[jj][r];
            }
        sloc += __shfl_xor(sloc, 16, 64);
        sloc += __shfl_xor(sloc, 32, 64);
        l_i = l_i * alpha + sloc;

        float ar[4];
#pragma unroll
        for (int r = 0; r < 4; ++r) ar[r] = __shfl(alpha, quad * 4 + r, 64);
#pragma unroll
        for (int dj = 0; dj < 4; ++dj)
#pragma unroll
            for (int r = 0; r < 4; ++r) oacc[dj][r] *= ar[r];

        _Float16* pw = &Pw[wave][0];
#pragma unroll
        for (int jj = 0; jj < 4; ++jj)
#pragma unroll
            for (int r = 0; r < 4; ++r)
                pw[ln15 * 72 + jj * 16 + quad * 4 + r] = (_Float16)p[jj][r];
        f16x8 pf[2];
#pragma unroll
        for (int ks = 0; ks < 2; ++ks)
            pf[ks] = *(const f16x8*)&pw[ln15 * 72 + ks * 32 + quad * 8];

#pragma unroll
        for (int dj = 0; dj < 4; ++dj)
#pragma unroll
            for (int ks = 0; ks < 2; ++ks) {
                f16x8 vf = *(const f16x8*)&VTs[(dj * 16 + ln15) * 72 + ks * 32 + quad * 8];
                oacc[dj] = __builtin_amdgcn_mfma_f32_16x16x32_f16(pf[ks], vf, oacc[dj], 0, 0, 0);
            }
        __syncthreads();
    }

    float linv[4];
#pragma unroll
    for (int r = 0; r < 4; ++r) linv[r] = 1.f / __shfl(l_i, quad * 4 + r, 64);
#pragma unroll
    for (int dj = 0; dj < 4; ++dj)
#pragma unroll
        for (int r = 0; r < 4; ++r) {
            int row = q0 + wave * 16 + quad * 4 + r;
            if (row < SEQ)
                ctx[(size_t)(b * SEQ + row) * 512 + h * 64 + dj * 16 + ln15] =
                    (_Float16)(oacc[dj][r] * linv[r]);
        }
}

// ---------------------------------------------------------------------------
// Head
// ---------------------------------------------------------------------------
__global__ __launch_bounds__(64) void head1_kernel(
    const float* __restrict__ x, const float* __restrict__ w,
    float* __restrict__ hmlp)
{
    const int n = blockIdx.x & 1023;
    const int b = blockIdx.x >> 10;
    const int t = threadIdx.x;
    const float4* cls = (const float4*)(x + (size_t)b * SEQ * 512);
    const float4* wr = (const float4*)(w + (size_t)n * 512);
    float s = 0.f;
#pragma unroll
    for (int i = 0; i < 2; ++i) {
        float4 a = cls[t + i * 64], c = wr[t + i * 64];
        s += a.x * c.x + a.y * c.y + a.z * c.z + a.w * c.w;
    }
#pragma unroll
    for (int o = 32; o; o >>= 1) s += __shfl_xor(s, o, 64);
    if (t == 0) hmlp[b * 1024 + n] = gelu_f(s);
}

__global__ __launch_bounds__(256) void head2_kernel(
    const float* __restrict__ hmlp, const float* __restrict__ w,
    float* __restrict__ out)
{
    __shared__ float red[4];
    const int b = blockIdx.x;
    const int t = threadIdx.x;
    float s = 0.f;
    for (int i = t; i < 1024; i += 256) s += hmlp[b * 1024 + i] * w[i];
#pragma unroll
    for (int o = 32; o; o >>= 1) s += __shfl_xor(s, o, 64);
    if ((t & 63) == 0) red[t >> 6] = s;
    __syncthreads();
    if (t == 0) out[b] = red[0] + red[1] + red[2] + red[3];
}

// ---------------------------------------------------------------------------
extern "C" void kernel_launch(void* const* d_in, const int* in_sizes, int n_in,
                              void* d_out, int out_size, void* d_ws, size_t ws_size,
                              hipStream_t stream)
{
    const float* feat_org = (const float*)d_in[0];
    const float* feat_r1  = (const float*)d_in[1];
    const float* feat_r2  = (const float*)d_in[2];
    const float* conv_w   = (const float*)d_in[3];
    const float* conv_b   = (const float*)d_in[4];
    const float* emb_org  = (const float*)d_in[5];
    const float* emb_r1   = (const float*)d_in[6];
    const float* emb_r2   = (const float*)d_in[7];
    const float* pos_emb  = (const float*)d_in[8];
    const float* cls_tok  = (const float*)d_in[9];
    const float* Wq = (const float*)d_in[10];
    const float* bq = (const float*)d_in[11];
    const float* Wk = (const float*)d_in[12];
    const float* bk = (const float*)d_in[13];
    const float* Wv = (const float*)d_in[14];
    const float* bv = (const float*)d_in[15];
    const float* Wo = (const float*)d_in[16];
    const float* bo = (const float*)d_in[17];
    const float* ln1g = (const float*)d_in[18];
    const float* ln1b = (const float*)d_in[19];
    const float* w1 = (const float*)d_in[20];
    const float* b1 = (const float*)d_in[21];
    const float* w2 = (const float*)d_in[22];
    const float* b2 = (const float*)d_in[23];
    const float* ln2g = (const float*)d_in[24];
    const float* ln2b = (const float*)d_in[25];
    const float* pw1 = (const float*)d_in[26];
    const float* pw2 = (const float*)d_in[27];
    const int*   mask = (const int*)d_in[28];

    // -------- workspace layout (~94.8 MB; R4's proven 108.2 MB fit) ----
    char* base = (char*)d_ws;
    _Float16* ffh16 = (_Float16*)base;                    // 29,884,416 (patch16 in embed)
    _Float16* patch16 = ffh16;
    base += (size_t)7296 * 2048 * 2;
    float* x = (float*)base; base += (size_t)7296 * 512 * 4;          // 14,942,208
    _Float16* qk16 = (_Float16*)base; base += (size_t)7296 * 1024 * 2; // 14,942,208 (Q|K, ld=1024)
    _Float16* vT16 = (_Float16*)base; base += (size_t)8 * 8 * 64 * 960 * 2; // 7,864,320
    _Float16* ctx16 = (_Float16*)base; base += (size_t)7296 * 512 * 2;      // 7,471,104
    _Float16* x16   = (_Float16*)base; base += (size_t)7296 * 512 * 2;      // 7,471,104
    _Float16* wqkv_all = (_Float16*)base; base += (size_t)6 * 1536 * 512 * 2; // 9,437,184
    _Float16* wo_all   = (_Float16*)base; base += (size_t)6 * 512 * 512 * 2;  // 3,145,728
    _Float16* w1_l16   = (_Float16*)base; base += (size_t)2048 * 512 * 2;     // 2,097,152
    _Float16* w2_l16   = (_Float16*)base; base += (size_t)512 * 2048 * 2;     // 2,097,152
    float* bqkv_all = (float*)base; base += 6 * 1536 * 4;
    float* hmlp = (float*)base; base += 8 * 1024 * 4;

    // fp32 split-K partial overlays (dead regions at time of use):
    //  - O-proj partials: ffh region (2*7296*512*4 = 29,884,416 B, exact fit)
    //  - FFN2 + embed partials: qk16+vT16+ctx16 contiguous (30,277,632 B)
    float* partO = (float*)ffh16;
    float* partF = (float*)qk16;
    // convw16 lives in x16 region during embed (x16 first written after embed gemm)
    _Float16* convw16 = x16;

    // -------- prep --------
    dim3 tb(32, 8);
    hipLaunchKernelGGL(transpose_feat_kernel, dim3(24, 64, 8), tb, 0, stream,
                       feat_org, patch16, 768, 0);
    hipLaunchKernelGGL(transpose_feat_kernel, dim3(4, 64, 8), tb, 0, stream,
                       feat_r1, patch16, 108, 768);
    hipLaunchKernelGGL(transpose_feat_kernel, dim3(2, 64, 8), tb, 0, stream,
                       feat_r2, patch16, 35, 876);
    hipLaunchKernelGGL(cast16_kernel, dim3(1024), 256, 0, stream,
                       conv_w, convw16, 512 * 2048 / 4);
    hipLaunchKernelGGL(cast16_kernel, dim3(1536), 256, 0, stream,
                       Wo, wo_all, 6 * 512 * 512 / 4);
    hipLaunchKernelGGL(pack_qkvw_kernel, dim3(4608), 256, 0, stream,
                       Wq, Wk, Wv, wqkv_all);
    hipLaunchKernelGGL(pack_qkvb_kernel, dim3(36), 256, 0, stream,
                       bq, bk, bv, bqkv_all);

    // -------- embed --------
    hipLaunchKernelGGL(gemm16_splitk, dim3(8, 57, 2), 256, 0, stream,
                       patch16, convw16, partF, 7288, 512, 2048);
    hipLaunchKernelGGL(build_x_red, dim3(7296), 128, 0, stream,
                       partF, conv_b, cls_tok, emb_org, emb_r1, emb_r2, pos_emb, x, x16);

    // -------- layers --------
    for (int l = 0; l < NLAYER; ++l) {
        hipLaunchKernelGGL(cast2_kernel, dim3(2048), 256, 0, stream,
                           w1 + (size_t)l * 2048 * 512, w1_l16, 2048 * 512 / 4,
                           w2 + (size_t)l * 512 * 2048, w2_l16, 512 * 2048 / 4);
        hipLaunchKernelGGL((gemm16<0, 1>), dim3(12, 57), 256, 0, stream,
                           x16, wqkv_all + (size_t)l * 1536 * 512, bqkv_all + l * 1536,
                           qk16, vT16, 7296, 1536, 512, 1024);
        hipLaunchKernelGGL(attn_mfma, dim3(15, 8, 8), 256, 0, stream,
                           qk16, vT16, mask, ctx16);
        hipLaunchKernelGGL(gemm16_splitk, dim3(8, 57, 2), 256, 0, stream,
                           ctx16, wo_all + (size_t)l * 512 * 512, partO, 7296, 512, 512);
        hipLaunchKernelGGL(ln_residual_red, dim3(7296), 64, 0, stream,
                           x, x16, partO, bo + l * 512, ln1g + l * 512, ln1b + l * 512);
        hipLaunchKernelGGL((gemm16<1, 0>), dim3(16, 57), 256, 0, stream,
                           x16, w1_l16, b1 + l * 2048,
                           ffh16, (_Float16*)nullptr, 7296, 2048, 512, 2048);
        hipLaunchKernelGGL(gemm16_splitk, dim3(8, 57, 2), 256, 0, stream,
                           ffh16, w2_l16, partF, 7296, 512, 2048);
        hipLaunchKernelGGL(ln_residual_red, dim3(7296), 64, 0, stream,
                           x, x16, partF, b2 + l * 512, ln2g + l * 512, ln2b + l * 512);
    }

    hipLaunchKernelGGL(head1_kernel, dim3(8 * 1024), 64, 0, stream, x, pw1, hmlp);
    hipLaunchKernelGGL(head2_kernel, dim3(8), 256, 0, stream, hmlp, pw2, (float*)d_out);
}